// Round 1
// baseline (550.468 us; speedup 1.0000x reference)
//
#include <hip/hip_runtime.h>
#include <hip/hip_bf16.h>

// ---------------------------------------------------------------------------
// GCN link prediction:
//   deg -> CSR build -> (X@W1) -> aggregate+bias+relu -> (@W2) -> aggregate+bias
//   -> decode: out[e] = dot(z[src], z[dst])
// All fp32. Indices arrive as int32 per harness convention.
// ---------------------------------------------------------------------------

__global__ __launch_bounds__(256)
void count_kernel(const int* __restrict__ col, int* __restrict__ cnt, int ne) {
  int e = blockIdx.x * 256 + threadIdx.x;
  if (e < ne) atomicAdd(&cnt[col[e]], 1);
}

__global__ __launch_bounds__(256)
void deg_kernel(const int* __restrict__ cnt, float* __restrict__ dis,
                float* __restrict__ dinv, int n) {
  int i = blockIdx.x * 256 + threadIdx.x;
  if (i < n) {
    float d = (float)(cnt[i] + 1);   // +1 self loop
    dinv[i] = 1.0f / d;
    dis[i]  = rsqrtf(d);
  }
}

// Single-block exclusive scan of cnt[0..n) -> row_ptr, writes row_ptr[n]=total,
// then zeroes cnt (reused as scatter cursor).
__global__ __launch_bounds__(1024)
void scan_kernel(int* __restrict__ cnt, int* __restrict__ row_ptr, int n) {
  __shared__ int sA[1024], sB[1024];
  const int t = threadIdx.x;
  const int CHUNK = (n + 1023) >> 10;
  const int base = t * CHUNK;
  int sum = 0;
  for (int i = 0; i < CHUNK; ++i) {
    int idx = base + i;
    if (idx < n) sum += cnt[idx];
  }
  sA[t] = sum;
  __syncthreads();
  int* src = sA; int* dst = sB;
  for (int off = 1; off < 1024; off <<= 1) {
    int v = src[t];
    if (t >= off) v += src[t - off];
    dst[t] = v;
    __syncthreads();
    int* tmp = src; src = dst; dst = tmp;
  }
  int run = (t == 0) ? 0 : src[t - 1];
  for (int i = 0; i < CHUNK; ++i) {
    int idx = base + i;
    if (idx < n) { row_ptr[idx] = run; run += cnt[idx]; }
  }
  if (t == 1023) row_ptr[n] = src[1023];
  __syncthreads();
  for (int i = 0; i < CHUNK; ++i) {
    int idx = base + i;
    if (idx < n) cnt[idx] = 0;
  }
}

__global__ __launch_bounds__(256)
void fill_kernel(const int* __restrict__ row, const int* __restrict__ col,
                 const float* __restrict__ dis, const int* __restrict__ row_ptr,
                 int* __restrict__ cur, int* __restrict__ esrc,
                 float* __restrict__ enorm, int ne) {
  int e = blockIdx.x * 256 + threadIdx.x;
  if (e >= ne) return;
  int r = row[e], c = col[e];
  int pos = row_ptr[c] + atomicAdd(&cur[c], 1);
  esrc[pos]  = r;
  enorm[pos] = dis[r] * dis[c];
}

// Y[N,M] = X[N,128] @ W[128,M]   (fp32, W in LDS, 32-row X tile in padded LDS)
template<int M>
__global__ __launch_bounds__(256)
void gemm_kernel(const float* __restrict__ X, const float* __restrict__ W,
                 float* __restrict__ Y, int N) {
  constexpr int K = 128;
  constexpr int ROWS = 32;
  constexpr int XLD = K + 4;  // pad: keeps 16B alignment, breaks bank aliasing
  __shared__ float Ws[K * M];
  __shared__ float Xs[ROWS * XLD];
  const int t = threadIdx.x;
  for (int i = t; i < K * M / 4; i += 256)
    ((float4*)Ws)[i] = ((const float4*)W)[i];
  const int row0 = blockIdx.x * ROWS;
  for (int i = t; i < ROWS * K / 4; i += 256) {
    int r  = i >> 5;    // 32 float4 per row
    int c4 = i & 31;
    int gr = row0 + r;
    float4 v = make_float4(0.f, 0.f, 0.f, 0.f);
    if (gr < N) v = ((const float4*)(X + (size_t)gr * K))[c4];
    *(float4*)(&Xs[r * XLD + c4 * 4]) = v;
  }
  __syncthreads();
  constexpr int CGS = M / 4;               // col groups (4 cols each)
  constexpr int RPT = ROWS / (256 / CGS);  // 128 -> 4 rows/thread, 64 -> 2
  const int cg = t % CGS;
  const int rg = t / CGS;
  const int c0 = cg * 4;
  const int r0 = rg * RPT;
  float acc[RPT][4];
#pragma unroll
  for (int i = 0; i < RPT; ++i)
    acc[i][0] = acc[i][1] = acc[i][2] = acc[i][3] = 0.f;
#pragma unroll 4
  for (int k = 0; k < K; ++k) {
    float4 wv = *(const float4*)(&Ws[k * M + c0]);
#pragma unroll
    for (int i = 0; i < RPT; ++i) {
      float xv = Xs[(r0 + i) * XLD + k];
      acc[i][0] = fmaf(xv, wv.x, acc[i][0]);
      acc[i][1] = fmaf(xv, wv.y, acc[i][1]);
      acc[i][2] = fmaf(xv, wv.z, acc[i][2]);
      acc[i][3] = fmaf(xv, wv.w, acc[i][3]);
    }
  }
#pragma unroll
  for (int i = 0; i < RPT; ++i) {
    int gr = row0 + r0 + i;
    if (gr < N)
      *(float4*)(&Y[(size_t)gr * M + c0]) =
          make_float4(acc[i][0], acc[i][1], acc[i][2], acc[i][3]);
  }
}

// One wave per destination node; lanes cover channels.
// out[node] = sum_{edges} norm * xw[src] + deg_inv[node]*xw[node] + bias  (opt relu)
template<int CH, bool RELU>
__global__ __launch_bounds__(256)
void agg_kernel(const float* __restrict__ xw, const int* __restrict__ row_ptr,
                const int* __restrict__ esrc, const float* __restrict__ enorm,
                const float* __restrict__ deg_inv, const float* __restrict__ bias,
                float* __restrict__ out, int n) {
  int wave = (blockIdx.x * 256 + threadIdx.x) >> 6;
  int lane = threadIdx.x & 63;
  if (wave >= n) return;
  const int node = wave;
  const int s0 = row_ptr[node], s1 = row_ptr[node + 1];
  if (CH == 128) {
    float2 acc = make_float2(0.f, 0.f);
    for (int j = s0; j < s1; ++j) {
      int s = esrc[j];
      float w = enorm[j];
      float2 v = ((const float2*)(xw + (size_t)s * 128))[lane];
      acc.x = fmaf(w, v.x, acc.x);
      acc.y = fmaf(w, v.y, acc.y);
    }
    float di = deg_inv[node];
    float2 sv = ((const float2*)(xw + (size_t)node * 128))[lane];
    float2 bv = ((const float2*)bias)[lane];
    float ox = acc.x + sv.x * di + bv.x;
    float oy = acc.y + sv.y * di + bv.y;
    if (RELU) { ox = fmaxf(ox, 0.f); oy = fmaxf(oy, 0.f); }
    ((float2*)(out + (size_t)node * 128))[lane] = make_float2(ox, oy);
  } else {
    float acc = 0.f;
    for (int j = s0; j < s1; ++j) {
      int s = esrc[j];
      float w = enorm[j];
      acc = fmaf(w, xw[(size_t)s * 64 + lane], acc);
    }
    float di = deg_inv[node];
    float o = acc + xw[(size_t)node * 64 + lane] * di + bias[lane];
    if (RELU) o = fmaxf(o, 0.f);
    out[(size_t)node * 64 + lane] = o;
  }
}

// One wave per label edge: dot(z[src], z[dst]) over 64 channels.
__global__ __launch_bounds__(256)
void decode_kernel(const float* __restrict__ z, const int* __restrict__ eli,
                   float* __restrict__ out, int nl) {
  int wave = (blockIdx.x * 256 + threadIdx.x) >> 6;
  int lane = threadIdx.x & 63;
  if (wave >= nl) return;
  int src = eli[wave];
  int dst = eli[nl + wave];
  float p = z[(size_t)src * 64 + lane] * z[(size_t)dst * 64 + lane];
#pragma unroll
  for (int m = 32; m >= 1; m >>= 1) p += __shfl_xor(p, m, 64);
  if (lane == 0) out[wave] = p;
}

extern "C" void kernel_launch(void* const* d_in, const int* in_sizes, int n_in,
                              void* d_out, int out_size, void* d_ws, size_t ws_size,
                              hipStream_t stream) {
  const float* x  = (const float*)d_in[0];
  const float* W1 = (const float*)d_in[1];
  const float* b1 = (const float*)d_in[2];
  const float* W2 = (const float*)d_in[3];
  const float* b2 = (const float*)d_in[4];
  const int* eidx = (const int*)d_in[5];
  const int* eli  = (const int*)d_in[6];
  const int N  = in_sizes[0] / 128;
  const int E  = in_sizes[5] / 2;
  const int NL = in_sizes[6] / 2;
  float* out = (float*)d_out;

  char* ws = (char*)d_ws;
  size_t off = 0;
  auto alloc = [&](size_t bytes) -> char* {
    char* p = ws + off;
    off = (off + bytes + 255) & ~(size_t)255;
    return p;
  };
  float* dis   = (float*)alloc((size_t)N * 4);
  float* dinv  = (float*)alloc((size_t)N * 4);
  int*   cnt   = (int*)  alloc((size_t)N * 4);
  int*   rowp  = (int*)  alloc((size_t)(N + 1) * 4);
  int*   esrc  = (int*)  alloc((size_t)E * 4);
  float* enorm = (float*)alloc((size_t)E * 4);
  float* bufA  = (float*)alloc((size_t)N * 128 * 4);
  float* bufB  = (float*)alloc((size_t)N * 128 * 4);
  (void)ws_size; (void)n_in; (void)out_size;

  const int* row = eidx;      // edge_index[0]
  const int* col = eidx + E;  // edge_index[1]

  hipMemsetAsync(cnt, 0, (size_t)N * 4, stream);
  count_kernel<<<(E + 255) / 256, 256, 0, stream>>>(col, cnt, E);
  deg_kernel<<<(N + 255) / 256, 256, 0, stream>>>(cnt, dis, dinv, N);
  scan_kernel<<<1, 1024, 0, stream>>>(cnt, rowp, N);
  fill_kernel<<<(E + 255) / 256, 256, 0, stream>>>(row, col, dis, rowp, cnt,
                                                   esrc, enorm, E);
  // conv1: bufA = x@W1 ; bufB = relu(agg(bufA) + dinv*bufA + b1)
  gemm_kernel<128><<<(N + 31) / 32, 256, 0, stream>>>(x, W1, bufA, N);
  agg_kernel<128, true><<<(N + 3) / 4, 256, 0, stream>>>(bufA, rowp, esrc, enorm,
                                                         dinv, b1, bufB, N);
  // conv2: bufA[:N*64] = bufB@W2 ; bufB[:N*64] = agg(bufA) + dinv*bufA + b2
  gemm_kernel<64><<<(N + 31) / 32, 256, 0, stream>>>(bufB, W2, bufA, N);
  agg_kernel<64, false><<<(N + 3) / 4, 256, 0, stream>>>(bufA, rowp, esrc, enorm,
                                                         dinv, b2, bufB, N);
  // decode
  decode_kernel<<<(NL + 3) / 4, 256, 0, stream>>>(bufB, eli, out, NL);
}

// Round 2
// 370.710 us; speedup vs baseline: 1.4849x; 1.4849x over previous
//
#include <hip/hip_runtime.h>
#include <hip/hip_bf16.h>

// ---------------------------------------------------------------------------
// GCN link prediction:
//   deg+partials -> scan(2-level) -> CSR fill (packed int2) ->
//   (X@W1) -> agg+bias+relu -> (@W2) -> agg+bias -> decode dot
// All fp32.
// ---------------------------------------------------------------------------

__global__ __launch_bounds__(256)
void count_kernel(const int* __restrict__ col, int* __restrict__ cnt, int ne) {
  int e = blockIdx.x * 256 + threadIdx.x;
  if (e < ne) atomicAdd(&cnt[col[e]], 1);
}

// Per-block partial sums of cnt (256 elems/block) + degree terms.
__global__ __launch_bounds__(256)
void partial_deg_kernel(const int* __restrict__ cnt, int* __restrict__ part,
                        float* __restrict__ dis, float* __restrict__ dinv, int n) {
  int i = blockIdx.x * 256 + threadIdx.x;
  int c = (i < n) ? cnt[i] : 0;
  if (i < n) {
    float d = (float)(c + 1);   // +1 self loop
    dinv[i] = 1.0f / d;
    dis[i]  = rsqrtf(d);
  }
  int lane = threadIdx.x & 63, w = threadIdx.x >> 6;
  int s = c;
#pragma unroll
  for (int m = 32; m >= 1; m >>= 1) s += __shfl_xor(s, m, 64);
  __shared__ int wp[4];
  if (lane == 0) wp[w] = s;
  __syncthreads();
  if (threadIdx.x == 0) part[blockIdx.x] = wp[0] + wp[1] + wp[2] + wp[3];
}

__device__ inline int wave_incl_scan(int v, int lane) {
#pragma unroll
  for (int off = 1; off < 64; off <<= 1) {
    int u = __shfl_up(v, off, 64);
    if (lane >= off) v += u;
  }
  return v;
}

// Exclusive scan of part[0..nb), nb <= 256, one block of 256.
__global__ __launch_bounds__(256)
void scan_part_kernel(int* __restrict__ part, int nb) {
  int t = threadIdx.x;
  int v = (t < nb) ? part[t] : 0;
  int lane = t & 63, w = t >> 6;
  int inc = wave_incl_scan(v, lane);
  __shared__ int wp[4];
  if (lane == 63) wp[w] = inc;
  __syncthreads();
  if (t == 0) { int s = 0; for (int k = 0; k < 4; ++k) { int x = wp[k]; wp[k] = s; s += x; } }
  __syncthreads();
  int excl = wp[w] + inc - v;
  if (t < nb) part[t] = excl;
}

// row_ptr[i] = part[blk] + exclusive-scan-in-block(cnt); zero cnt (reused cursor).
__global__ __launch_bounds__(256)
void scan_final_kernel(const int* __restrict__ cnt, const int* __restrict__ part,
                       int* __restrict__ row_ptr, int* __restrict__ cur, int n) {
  int t = threadIdx.x;
  int i = blockIdx.x * 256 + t;
  int v = (i < n) ? cnt[i] : 0;
  int lane = t & 63, w = t >> 6;
  int inc = wave_incl_scan(v, lane);
  __shared__ int wp[4];
  if (lane == 63) wp[w] = inc;
  __syncthreads();
  if (t == 0) { int s = 0; for (int k = 0; k < 4; ++k) { int x = wp[k]; wp[k] = s; s += x; } }
  __syncthreads();
  int excl = part[blockIdx.x] + wp[w] + inc - v;
  if (i < n) {
    row_ptr[i] = excl;
    cur[i] = 0;
    if (i == n - 1) row_ptr[n] = excl + v;
  }
}

// Scatter edges into CSR slots; packed {src, norm-as-bits} single 8B write.
__global__ __launch_bounds__(256)
void fill_kernel(const int* __restrict__ row, const int* __restrict__ col,
                 const float* __restrict__ dis, const int* __restrict__ row_ptr,
                 int* __restrict__ cur, int2* __restrict__ ep, int ne) {
  int e = blockIdx.x * 256 + threadIdx.x;
  if (e >= ne) return;
  int r = row[e], c = col[e];
  int pos = row_ptr[c] + atomicAdd(&cur[c], 1);
  float nrm = dis[r] * dis[c];
  ep[pos] = make_int2(r, __float_as_int(nrm));
}

// Y[N,M] = X[N,128] @ W[128,M]   (fp32, W in LDS, 32-row X tile in padded LDS)
template<int M>
__global__ __launch_bounds__(256)
void gemm_kernel(const float* __restrict__ X, const float* __restrict__ W,
                 float* __restrict__ Y, int N) {
  constexpr int K = 128;
  constexpr int ROWS = 32;
  constexpr int XLD = K + 4;
  __shared__ float Ws[K * M];
  __shared__ float Xs[ROWS * XLD];
  const int t = threadIdx.x;
  for (int i = t; i < K * M / 4; i += 256)
    ((float4*)Ws)[i] = ((const float4*)W)[i];
  const int row0 = blockIdx.x * ROWS;
  for (int i = t; i < ROWS * K / 4; i += 256) {
    int r  = i >> 5;
    int c4 = i & 31;
    int gr = row0 + r;
    float4 v = make_float4(0.f, 0.f, 0.f, 0.f);
    if (gr < N) v = ((const float4*)(X + (size_t)gr * K))[c4];
    *(float4*)(&Xs[r * XLD + c4 * 4]) = v;
  }
  __syncthreads();
  constexpr int CGS = M / 4;
  constexpr int RPT = ROWS / (256 / CGS);
  const int cg = t % CGS;
  const int rg = t / CGS;
  const int c0 = cg * 4;
  const int r0 = rg * RPT;
  float acc[RPT][4];
#pragma unroll
  for (int i = 0; i < RPT; ++i)
    acc[i][0] = acc[i][1] = acc[i][2] = acc[i][3] = 0.f;
#pragma unroll 4
  for (int k = 0; k < K; ++k) {
    float4 wv = *(const float4*)(&Ws[k * M + c0]);
#pragma unroll
    for (int i = 0; i < RPT; ++i) {
      float xv = Xs[(r0 + i) * XLD + k];
      acc[i][0] = fmaf(xv, wv.x, acc[i][0]);
      acc[i][1] = fmaf(xv, wv.y, acc[i][1]);
      acc[i][2] = fmaf(xv, wv.z, acc[i][2]);
      acc[i][3] = fmaf(xv, wv.w, acc[i][3]);
    }
  }
#pragma unroll
  for (int i = 0; i < RPT; ++i) {
    int gr = row0 + r0 + i;
    if (gr < N)
      *(float4*)(&Y[(size_t)gr * M + c0]) =
          make_float4(acc[i][0], acc[i][1], acc[i][2], acc[i][3]);
  }
}

// One wave per node; lanes cover channels. Edge metadata batch-loaded by
// lanes (coalesced) and broadcast via shuffle; 2-way unroll for MLP.
template<int CH, bool RELU>
__global__ __launch_bounds__(256)
void agg_kernel(const float* __restrict__ xw, const int* __restrict__ row_ptr,
                const int2* __restrict__ ep, const float* __restrict__ deg_inv,
                const float* __restrict__ bias, float* __restrict__ out, int n) {
  int wave = (blockIdx.x * 256 + threadIdx.x) >> 6;
  int lane = threadIdx.x & 63;
  if (wave >= n) return;
  const int node = wave;
  const int s0 = row_ptr[node], s1 = row_ptr[node + 1];
  float2 a0 = make_float2(0.f, 0.f), a1 = make_float2(0.f, 0.f);
  float b0 = 0.f, b1 = 0.f;
  for (int base = s0; base < s1; base += 64) {
    int m = s1 - base; if (m > 64) m = 64;
    int2 ed = make_int2(0, 0);
    if (lane < m) ed = ep[base + lane];
    int k = 0;
    for (; k + 1 < m; k += 2) {
      int   sa = __shfl(ed.x, k, 64);
      float wa = __int_as_float(__shfl(ed.y, k, 64));
      int   sb = __shfl(ed.x, k + 1, 64);
      float wb = __int_as_float(__shfl(ed.y, k + 1, 64));
      if (CH == 128) {
        float2 va = ((const float2*)(xw + (size_t)sa * 128))[lane];
        float2 vb = ((const float2*)(xw + (size_t)sb * 128))[lane];
        a0.x = fmaf(wa, va.x, a0.x); a0.y = fmaf(wa, va.y, a0.y);
        a1.x = fmaf(wb, vb.x, a1.x); a1.y = fmaf(wb, vb.y, a1.y);
      } else {
        b0 = fmaf(wa, xw[(size_t)sa * 64 + lane], b0);
        b1 = fmaf(wb, xw[(size_t)sb * 64 + lane], b1);
      }
    }
    if (k < m) {
      int   sa = __shfl(ed.x, k, 64);
      float wa = __int_as_float(__shfl(ed.y, k, 64));
      if (CH == 128) {
        float2 va = ((const float2*)(xw + (size_t)sa * 128))[lane];
        a0.x = fmaf(wa, va.x, a0.x); a0.y = fmaf(wa, va.y, a0.y);
      } else {
        b0 = fmaf(wa, xw[(size_t)sa * 64 + lane], b0);
      }
    }
  }
  float di = deg_inv[node];
  if (CH == 128) {
    float2 sv = ((const float2*)(xw + (size_t)node * 128))[lane];
    float2 bv = ((const float2*)bias)[lane];
    float ox = (a0.x + a1.x) + sv.x * di + bv.x;
    float oy = (a0.y + a1.y) + sv.y * di + bv.y;
    if (RELU) { ox = fmaxf(ox, 0.f); oy = fmaxf(oy, 0.f); }
    ((float2*)(out + (size_t)node * 128))[lane] = make_float2(ox, oy);
  } else {
    float o = (b0 + b1) + xw[(size_t)node * 64 + lane] * di + bias[lane];
    if (RELU) o = fmaxf(o, 0.f);
    out[(size_t)node * 64 + lane] = o;
  }
}

// One wave per label edge: dot(z[src], z[dst]) over 64 channels.
__global__ __launch_bounds__(256)
void decode_kernel(const float* __restrict__ z, const int* __restrict__ eli,
                   float* __restrict__ out, int nl) {
  int wave = (blockIdx.x * 256 + threadIdx.x) >> 6;
  int lane = threadIdx.x & 63;
  if (wave >= nl) return;
  int src = eli[wave];
  int dst = eli[nl + wave];
  float p = z[(size_t)src * 64 + lane] * z[(size_t)dst * 64 + lane];
#pragma unroll
  for (int m = 32; m >= 1; m >>= 1) p += __shfl_xor(p, m, 64);
  if (lane == 0) out[wave] = p;
}

extern "C" void kernel_launch(void* const* d_in, const int* in_sizes, int n_in,
                              void* d_out, int out_size, void* d_ws, size_t ws_size,
                              hipStream_t stream) {
  const float* x  = (const float*)d_in[0];
  const float* W1 = (const float*)d_in[1];
  const float* b1 = (const float*)d_in[2];
  const float* W2 = (const float*)d_in[3];
  const float* b2 = (const float*)d_in[4];
  const int* eidx = (const int*)d_in[5];
  const int* eli  = (const int*)d_in[6];
  const int N  = in_sizes[0] / 128;
  const int E  = in_sizes[5] / 2;
  const int NL = in_sizes[6] / 2;
  float* out = (float*)d_out;

  char* ws = (char*)d_ws;
  size_t off = 0;
  auto alloc = [&](size_t bytes) -> char* {
    char* p = ws + off;
    off = (off + bytes + 255) & ~(size_t)255;
    return p;
  };
  const int NB = (N + 255) / 256;  // 196 partial blocks
  float* dis   = (float*)alloc((size_t)N * 4);
  float* dinv  = (float*)alloc((size_t)N * 4);
  int*   cnt   = (int*)  alloc((size_t)N * 4);
  int*   rowp  = (int*)  alloc((size_t)(N + 1) * 4);
  int*   part  = (int*)  alloc((size_t)NB * 4);
  int2*  ep    = (int2*) alloc((size_t)E * 8);
  float* bufA  = (float*)alloc((size_t)N * 128 * 4);
  float* bufB  = (float*)alloc((size_t)N * 128 * 4);
  (void)ws_size; (void)n_in; (void)out_size;

  const int* row = eidx;      // edge_index[0]
  const int* col = eidx + E;  // edge_index[1]

  hipMemsetAsync(cnt, 0, (size_t)N * 4, stream);
  count_kernel<<<(E + 255) / 256, 256, 0, stream>>>(col, cnt, E);
  partial_deg_kernel<<<NB, 256, 0, stream>>>(cnt, part, dis, dinv, N);
  scan_part_kernel<<<1, 256, 0, stream>>>(part, NB);
  scan_final_kernel<<<NB, 256, 0, stream>>>(cnt, part, rowp, cnt, N);
  fill_kernel<<<(E + 255) / 256, 256, 0, stream>>>(row, col, dis, rowp, cnt, ep, E);
  // conv1: bufA = x@W1 ; bufB = relu(agg(bufA) + dinv*bufA + b1)
  gemm_kernel<128><<<(N + 31) / 32, 256, 0, stream>>>(x, W1, bufA, N);
  agg_kernel<128, true><<<(N + 3) / 4, 256, 0, stream>>>(bufA, rowp, ep, dinv, b1, bufB, N);
  // conv2: bufA[:N*64] = bufB@W2 ; bufB[:N*64] = agg(bufA) + dinv*bufA + b2
  gemm_kernel<64><<<(N + 31) / 32, 256, 0, stream>>>(bufB, W2, bufA, N);
  agg_kernel<64, false><<<(N + 3) / 4, 256, 0, stream>>>(bufA, rowp, ep, dinv, b2, bufB, N);
  // decode
  decode_kernel<<<(NL + 3) / 4, 256, 0, stream>>>(bufB, eli, out, NL);
}

// Round 4
// 338.156 us; speedup vs baseline: 1.6278x; 1.0963x over previous
//
#include <hip/hip_runtime.h>
#include <hip/hip_bf16.h>

// ---------------------------------------------------------------------------
// GCN link prediction:
//   deg+partials -> scan(2-level) -> CSR fill (packed int2) ->
//   (X@W1) -> agg+bias+relu -> (@W2) -> agg+bias -> decode dot
// All fp32. Round 4 = round-2 code with ONE change: gemm stages W in K=32
// chunks (LDS 82KB -> 33KB, 1 -> 4 blocks/CU). Accumulation order identical.
// ---------------------------------------------------------------------------

__global__ __launch_bounds__(256)
void count_kernel(const int* __restrict__ col, int* __restrict__ cnt, int ne) {
  int e = blockIdx.x * 256 + threadIdx.x;
  if (e < ne) atomicAdd(&cnt[col[e]], 1);
}

__global__ __launch_bounds__(256)
void partial_deg_kernel(const int* __restrict__ cnt, int* __restrict__ part,
                        float* __restrict__ dis, float* __restrict__ dinv, int n) {
  int i = blockIdx.x * 256 + threadIdx.x;
  int c = (i < n) ? cnt[i] : 0;
  if (i < n) {
    float d = (float)(c + 1);   // +1 self loop
    dinv[i] = 1.0f / d;
    dis[i]  = rsqrtf(d);
  }
  int lane = threadIdx.x & 63, w = threadIdx.x >> 6;
  int s = c;
#pragma unroll
  for (int m = 32; m >= 1; m >>= 1) s += __shfl_xor(s, m, 64);
  __shared__ int wp[4];
  if (lane == 0) wp[w] = s;
  __syncthreads();
  if (threadIdx.x == 0) part[blockIdx.x] = wp[0] + wp[1] + wp[2] + wp[3];
}

__device__ inline int wave_incl_scan(int v, int lane) {
#pragma unroll
  for (int off = 1; off < 64; off <<= 1) {
    int u = __shfl_up(v, off, 64);
    if (lane >= off) v += u;
  }
  return v;
}

__global__ __launch_bounds__(256)
void scan_part_kernel(int* __restrict__ part, int nb) {
  int t = threadIdx.x;
  int v = (t < nb) ? part[t] : 0;
  int lane = t & 63, w = t >> 6;
  int inc = wave_incl_scan(v, lane);
  __shared__ int wp[4];
  if (lane == 63) wp[w] = inc;
  __syncthreads();
  if (t == 0) { int s = 0; for (int k = 0; k < 4; ++k) { int x = wp[k]; wp[k] = s; s += x; } }
  __syncthreads();
  int excl = wp[w] + inc - v;
  if (t < nb) part[t] = excl;
}

__global__ __launch_bounds__(256)
void scan_final_kernel(const int* __restrict__ cnt, const int* __restrict__ part,
                       int* __restrict__ row_ptr, int* __restrict__ cur, int n) {
  int t = threadIdx.x;
  int i = blockIdx.x * 256 + t;
  int v = (i < n) ? cnt[i] : 0;
  int lane = t & 63, w = t >> 6;
  int inc = wave_incl_scan(v, lane);
  __shared__ int wp[4];
  if (lane == 63) wp[w] = inc;
  __syncthreads();
  if (t == 0) { int s = 0; for (int k = 0; k < 4; ++k) { int x = wp[k]; wp[k] = s; s += x; } }
  __syncthreads();
  int excl = part[blockIdx.x] + wp[w] + inc - v;
  if (i < n) {
    row_ptr[i] = excl;
    cur[i] = 0;
    if (i == n - 1) row_ptr[n] = excl + v;
  }
}

__global__ __launch_bounds__(256)
void fill_kernel(const int* __restrict__ row, const int* __restrict__ col,
                 const float* __restrict__ dis, const int* __restrict__ row_ptr,
                 int* __restrict__ cur, int2* __restrict__ ep, int ne) {
  int e = blockIdx.x * 256 + threadIdx.x;
  if (e >= ne) return;
  int r = row[e], c = col[e];
  int pos = row_ptr[c] + atomicAdd(&cur[c], 1);
  float nrm = dis[r] * dis[c];
  ep[pos] = make_int2(r, __float_as_int(nrm));
}

// Y[N,M] = X[N,128] @ W[128,M]. Round-2 structure; W staged in K=32 chunks.
// Per-output accumulation order (k=0..127 sequential) identical to round 2.
template<int M>
__global__ __launch_bounds__(256)
void gemm_kernel(const float* __restrict__ X, const float* __restrict__ W,
                 float* __restrict__ Y, int N) {
  constexpr int K = 128;
  constexpr int KC = 32;       // K chunk for W staging
  constexpr int ROWS = 32;
  constexpr int XLD = K + 4;   // 132: 16B-aligned rows, breaks bank aliasing
  __shared__ float Ws[KC * M];           // 16 KB (M=128) / 8 KB (M=64)
  __shared__ float Xs[ROWS * XLD];       // 16.9 KB
  const int t = threadIdx.x;
  const int row0 = blockIdx.x * ROWS;
  // stage X tile once: Xs[r][0..127] = X[row0+r][:]
  for (int i = t; i < ROWS * K / 4; i += 256) {
    int r  = i >> 5;    // 32 float4 per row
    int c4 = i & 31;
    int gr = row0 + r;
    float4 v = make_float4(0.f, 0.f, 0.f, 0.f);
    if (gr < N) v = ((const float4*)(X + (size_t)gr * K))[c4];
    *(float4*)(&Xs[r * XLD + c4 * 4]) = v;
  }
  constexpr int CGS = M / 4;               // col groups (4 cols each)
  constexpr int RPT = ROWS / (256 / CGS);  // M=128 -> 4 rows/thread, M=64 -> 2
  const int cg = t % CGS;
  const int rg = t / CGS;
  const int c0 = cg * 4;
  const int r0 = rg * RPT;
  float acc[RPT][4];
#pragma unroll
  for (int i = 0; i < RPT; ++i)
    acc[i][0] = acc[i][1] = acc[i][2] = acc[i][3] = 0.f;

  for (int k0 = 0; k0 < K; k0 += KC) {
    __syncthreads();   // protect Ws reuse (and Xs staging on first iter)
    for (int i = t; i < KC * M / 4; i += 256) {
      int kk = i / (M / 4), cc = i % (M / 4);
      ((float4*)&Ws[kk * M])[cc] = ((const float4*)&W[(size_t)(k0 + kk) * M])[cc];
    }
    __syncthreads();
#pragma unroll 4
    for (int k = 0; k < KC; ++k) {
      float4 wv = *(const float4*)(&Ws[k * M + c0]);
#pragma unroll
      for (int i = 0; i < RPT; ++i) {
        float xv = Xs[(r0 + i) * XLD + (k0 + k)];
        acc[i][0] = fmaf(xv, wv.x, acc[i][0]);
        acc[i][1] = fmaf(xv, wv.y, acc[i][1]);
        acc[i][2] = fmaf(xv, wv.z, acc[i][2]);
        acc[i][3] = fmaf(xv, wv.w, acc[i][3]);
      }
    }
  }
#pragma unroll
  for (int i = 0; i < RPT; ++i) {
    int gr = row0 + r0 + i;
    if (gr < N)
      *(float4*)(&Y[(size_t)gr * M + c0]) =
          make_float4(acc[i][0], acc[i][1], acc[i][2], acc[i][3]);
  }
}

// One wave per node; lanes cover channels. Edge metadata batch-loaded by
// lanes (coalesced) and broadcast via shuffle; 2-way unroll for MLP.
template<int CH, bool RELU>
__global__ __launch_bounds__(256)
void agg_kernel(const float* __restrict__ xw, const int* __restrict__ row_ptr,
                const int2* __restrict__ ep, const float* __restrict__ deg_inv,
                const float* __restrict__ bias, float* __restrict__ out, int n) {
  int wave = (blockIdx.x * 256 + threadIdx.x) >> 6;
  int lane = threadIdx.x & 63;
  if (wave >= n) return;
  const int node = wave;
  const int s0 = row_ptr[node], s1 = row_ptr[node + 1];
  float2 a0 = make_float2(0.f, 0.f), a1 = make_float2(0.f, 0.f);
  float b0 = 0.f, b1 = 0.f;
  for (int base = s0; base < s1; base += 64) {
    int m = s1 - base; if (m > 64) m = 64;
    int2 ed = make_int2(0, 0);
    if (lane < m) ed = ep[base + lane];
    int k = 0;
    for (; k + 1 < m; k += 2) {
      int   sa = __shfl(ed.x, k, 64);
      float wa = __int_as_float(__shfl(ed.y, k, 64));
      int   sb = __shfl(ed.x, k + 1, 64);
      float wb = __int_as_float(__shfl(ed.y, k + 1, 64));
      if (CH == 128) {
        float2 va = ((const float2*)(xw + (size_t)sa * 128))[lane];
        float2 vb = ((const float2*)(xw + (size_t)sb * 128))[lane];
        a0.x = fmaf(wa, va.x, a0.x); a0.y = fmaf(wa, va.y, a0.y);
        a1.x = fmaf(wb, vb.x, a1.x); a1.y = fmaf(wb, vb.y, a1.y);
      } else {
        b0 = fmaf(wa, xw[(size_t)sa * 64 + lane], b0);
        b1 = fmaf(wb, xw[(size_t)sb * 64 + lane], b1);
      }
    }
    if (k < m) {
      int   sa = __shfl(ed.x, k, 64);
      float wa = __int_as_float(__shfl(ed.y, k, 64));
      if (CH == 128) {
        float2 va = ((const float2*)(xw + (size_t)sa * 128))[lane];
        a0.x = fmaf(wa, va.x, a0.x); a0.y = fmaf(wa, va.y, a0.y);
      } else {
        b0 = fmaf(wa, xw[(size_t)sa * 64 + lane], b0);
      }
    }
  }
  float di = deg_inv[node];
  if (CH == 128) {
    float2 sv = ((const float2*)(xw + (size_t)node * 128))[lane];
    float2 bv = ((const float2*)bias)[lane];
    float ox = (a0.x + a1.x) + sv.x * di + bv.x;
    float oy = (a0.y + a1.y) + sv.y * di + bv.y;
    if (RELU) { ox = fmaxf(ox, 0.f); oy = fmaxf(oy, 0.f); }
    ((float2*)(out + (size_t)node * 128))[lane] = make_float2(ox, oy);
  } else {
    float o = (b0 + b1) + xw[(size_t)node * 64 + lane] * di + bias[lane];
    if (RELU) o = fmaxf(o, 0.f);
    out[(size_t)node * 64 + lane] = o;
  }
}

// One wave per label edge: dot(z[src], z[dst]) over 64 channels.
__global__ __launch_bounds__(256)
void decode_kernel(const float* __restrict__ z, const int* __restrict__ eli,
                   float* __restrict__ out, int nl) {
  int wave = (blockIdx.x * 256 + threadIdx.x) >> 6;
  int lane = threadIdx.x & 63;
  if (wave >= nl) return;
  int src = eli[wave];
  int dst = eli[nl + wave];
  float p = z[(size_t)src * 64 + lane] * z[(size_t)dst * 64 + lane];
#pragma unroll
  for (int m = 32; m >= 1; m >>= 1) p += __shfl_xor(p, m, 64);
  if (lane == 0) out[wave] = p;
}

extern "C" void kernel_launch(void* const* d_in, const int* in_sizes, int n_in,
                              void* d_out, int out_size, void* d_ws, size_t ws_size,
                              hipStream_t stream) {
  const float* x  = (const float*)d_in[0];
  const float* W1 = (const float*)d_in[1];
  const float* b1 = (const float*)d_in[2];
  const float* W2 = (const float*)d_in[3];
  const float* b2 = (const float*)d_in[4];
  const int* eidx = (const int*)d_in[5];
  const int* eli  = (const int*)d_in[6];
  const int N  = in_sizes[0] / 128;
  const int E  = in_sizes[5] / 2;
  const int NL = in_sizes[6] / 2;
  float* out = (float*)d_out;

  char* ws = (char*)d_ws;
  size_t off = 0;
  auto alloc = [&](size_t bytes) -> char* {
    char* p = ws + off;
    off = (off + bytes + 255) & ~(size_t)255;
    return p;
  };
  const int NB = (N + 255) / 256;
  float* dis   = (float*)alloc((size_t)N * 4);
  float* dinv  = (float*)alloc((size_t)N * 4);
  int*   cnt   = (int*)  alloc((size_t)N * 4);
  int*   rowp  = (int*)  alloc((size_t)(N + 1) * 4);
  int*   part  = (int*)  alloc((size_t)NB * 4);
  int2*  ep    = (int2*) alloc((size_t)E * 8);
  float* bufA  = (float*)alloc((size_t)N * 128 * 4);
  float* bufB  = (float*)alloc((size_t)N * 128 * 4);
  (void)ws_size; (void)n_in; (void)out_size;

  const int* row = eidx;      // edge_index[0]
  const int* col = eidx + E;  // edge_index[1]

  hipMemsetAsync(cnt, 0, (size_t)N * 4, stream);
  count_kernel<<<(E + 255) / 256, 256, 0, stream>>>(col, cnt, E);
  partial_deg_kernel<<<NB, 256, 0, stream>>>(cnt, part, dis, dinv, N);
  scan_part_kernel<<<1, 256, 0, stream>>>(part, NB);
  scan_final_kernel<<<NB, 256, 0, stream>>>(cnt, part, rowp, cnt, N);
  fill_kernel<<<(E + 255) / 256, 256, 0, stream>>>(row, col, dis, rowp, cnt, ep, E);
  // conv1
  gemm_kernel<128><<<(N + 31) / 32, 256, 0, stream>>>(x, W1, bufA, N);
  agg_kernel<128, true><<<(N + 3) / 4, 256, 0, stream>>>(bufA, rowp, ep, dinv, b1, bufB, N);
  // conv2
  gemm_kernel<64><<<(N + 31) / 32, 256, 0, stream>>>(bufB, W2, bufA, N);
  agg_kernel<64, false><<<(N + 3) / 4, 256, 0, stream>>>(bufA, rowp, ep, dinv, b2, bufB, N);
  // decode
  decode_kernel<<<(NL + 3) / 4, 256, 0, stream>>>(bufB, eli, out, NL);
}

// Round 6
// 332.127 us; speedup vs baseline: 1.6574x; 1.0182x over previous
//
#include <hip/hip_runtime.h>
#include <hip/hip_bf16.h>

// ---------------------------------------------------------------------------
// GCN link prediction:
//   deg+partials -> scan(2-level) -> CSR fill (packed int2) ->
//   (X@W1) -> agg+bias+relu -> (@W2) -> agg+bias -> decode dot
// All fp32. Round 6 = round-4 passing code with ONE change: agg edge loop
// unrolled 4-deep with 4 accumulator chains (uniform shfl broadcast indices,
// same pattern that passed in rounds 2/4; sub-wave split abandoned after two
// unexplained failures).
// ---------------------------------------------------------------------------

__global__ __launch_bounds__(256)
void count_kernel(const int* __restrict__ col, int* __restrict__ cnt, int ne) {
  int e = blockIdx.x * 256 + threadIdx.x;
  if (e < ne) atomicAdd(&cnt[col[e]], 1);
}

__global__ __launch_bounds__(256)
void partial_deg_kernel(const int* __restrict__ cnt, int* __restrict__ part,
                        float* __restrict__ dis, float* __restrict__ dinv, int n) {
  int i = blockIdx.x * 256 + threadIdx.x;
  int c = (i < n) ? cnt[i] : 0;
  if (i < n) {
    float d = (float)(c + 1);   // +1 self loop
    dinv[i] = 1.0f / d;
    dis[i]  = rsqrtf(d);
  }
  int lane = threadIdx.x & 63, w = threadIdx.x >> 6;
  int s = c;
#pragma unroll
  for (int m = 32; m >= 1; m >>= 1) s += __shfl_xor(s, m, 64);
  __shared__ int wp[4];
  if (lane == 0) wp[w] = s;
  __syncthreads();
  if (threadIdx.x == 0) part[blockIdx.x] = wp[0] + wp[1] + wp[2] + wp[3];
}

__device__ inline int wave_incl_scan(int v, int lane) {
#pragma unroll
  for (int off = 1; off < 64; off <<= 1) {
    int u = __shfl_up(v, off, 64);
    if (lane >= off) v += u;
  }
  return v;
}

__global__ __launch_bounds__(256)
void scan_part_kernel(int* __restrict__ part, int nb) {
  int t = threadIdx.x;
  int v = (t < nb) ? part[t] : 0;
  int lane = t & 63, w = t >> 6;
  int inc = wave_incl_scan(v, lane);
  __shared__ int wp[4];
  if (lane == 63) wp[w] = inc;
  __syncthreads();
  if (t == 0) { int s = 0; for (int k = 0; k < 4; ++k) { int x = wp[k]; wp[k] = s; s += x; } }
  __syncthreads();
  int excl = wp[w] + inc - v;
  if (t < nb) part[t] = excl;
}

__global__ __launch_bounds__(256)
void scan_final_kernel(const int* __restrict__ cnt, const int* __restrict__ part,
                       int* __restrict__ row_ptr, int* __restrict__ cur, int n) {
  int t = threadIdx.x;
  int i = blockIdx.x * 256 + t;
  int v = (i < n) ? cnt[i] : 0;
  int lane = t & 63, w = t >> 6;
  int inc = wave_incl_scan(v, lane);
  __shared__ int wp[4];
  if (lane == 63) wp[w] = inc;
  __syncthreads();
  if (t == 0) { int s = 0; for (int k = 0; k < 4; ++k) { int x = wp[k]; wp[k] = s; s += x; } }
  __syncthreads();
  int excl = part[blockIdx.x] + wp[w] + inc - v;
  if (i < n) {
    row_ptr[i] = excl;
    cur[i] = 0;
    if (i == n - 1) row_ptr[n] = excl + v;
  }
}

__global__ __launch_bounds__(256)
void fill_kernel(const int* __restrict__ row, const int* __restrict__ col,
                 const float* __restrict__ dis, const int* __restrict__ row_ptr,
                 int* __restrict__ cur, int2* __restrict__ ep, int ne) {
  int e = blockIdx.x * 256 + threadIdx.x;
  if (e >= ne) return;
  int r = row[e], c = col[e];
  int pos = row_ptr[c] + atomicAdd(&cur[c], 1);
  float nrm = dis[r] * dis[c];
  ep[pos] = make_int2(r, __float_as_int(nrm));
}

// Y[N,M] = X[N,128] @ W[128,M]. W staged in K=32 chunks (round-4, passing).
template<int M>
__global__ __launch_bounds__(256)
void gemm_kernel(const float* __restrict__ X, const float* __restrict__ W,
                 float* __restrict__ Y, int N) {
  constexpr int K = 128;
  constexpr int KC = 32;
  constexpr int ROWS = 32;
  constexpr int XLD = K + 4;
  __shared__ float Ws[KC * M];
  __shared__ float Xs[ROWS * XLD];
  const int t = threadIdx.x;
  const int row0 = blockIdx.x * ROWS;
  for (int i = t; i < ROWS * K / 4; i += 256) {
    int r  = i >> 5;
    int c4 = i & 31;
    int gr = row0 + r;
    float4 v = make_float4(0.f, 0.f, 0.f, 0.f);
    if (gr < N) v = ((const float4*)(X + (size_t)gr * K))[c4];
    *(float4*)(&Xs[r * XLD + c4 * 4]) = v;
  }
  constexpr int CGS = M / 4;
  constexpr int RPT = ROWS / (256 / CGS);
  const int cg = t % CGS;
  const int rg = t / CGS;
  const int c0 = cg * 4;
  const int r0 = rg * RPT;
  float acc[RPT][4];
#pragma unroll
  for (int i = 0; i < RPT; ++i)
    acc[i][0] = acc[i][1] = acc[i][2] = acc[i][3] = 0.f;

  for (int k0 = 0; k0 < K; k0 += KC) {
    __syncthreads();
    for (int i = t; i < KC * M / 4; i += 256) {
      int kk = i / (M / 4), cc = i % (M / 4);
      ((float4*)&Ws[kk * M])[cc] = ((const float4*)&W[(size_t)(k0 + kk) * M])[cc];
    }
    __syncthreads();
#pragma unroll 4
    for (int k = 0; k < KC; ++k) {
      float4 wv = *(const float4*)(&Ws[k * M + c0]);
#pragma unroll
      for (int i = 0; i < RPT; ++i) {
        float xv = Xs[(r0 + i) * XLD + (k0 + k)];
        acc[i][0] = fmaf(xv, wv.x, acc[i][0]);
        acc[i][1] = fmaf(xv, wv.y, acc[i][1]);
        acc[i][2] = fmaf(xv, wv.z, acc[i][2]);
        acc[i][3] = fmaf(xv, wv.w, acc[i][3]);
      }
    }
  }
#pragma unroll
  for (int i = 0; i < RPT; ++i) {
    int gr = row0 + r0 + i;
    if (gr < N)
      *(float4*)(&Y[(size_t)gr * M + c0]) =
          make_float4(acc[i][0], acc[i][1], acc[i][2], acc[i][3]);
  }
}

// One wave per node; lanes cover channels. Edge metadata batch-loaded by
// lanes (coalesced) and broadcast via UNIFORM-index shuffles; 4-way unroll
// with 4 independent accumulator chains for memory-level parallelism.
template<int CH, bool RELU>
__global__ __launch_bounds__(256)
void agg_kernel(const float* __restrict__ xw, const int* __restrict__ row_ptr,
                const int2* __restrict__ ep, const float* __restrict__ deg_inv,
                const float* __restrict__ bias, float* __restrict__ out, int n) {
  int wave = (blockIdx.x * 256 + threadIdx.x) >> 6;
  int lane = threadIdx.x & 63;
  if (wave >= n) return;
  const int node = wave;
  const int s0 = row_ptr[node], s1 = row_ptr[node + 1];
  float2 a0 = make_float2(0.f, 0.f), a1 = make_float2(0.f, 0.f);
  float2 a2 = make_float2(0.f, 0.f), a3 = make_float2(0.f, 0.f);
  float b0 = 0.f, b1 = 0.f, b2 = 0.f, b3 = 0.f;
  for (int base = s0; base < s1; base += 64) {
    int m = s1 - base; if (m > 64) m = 64;
    int2 ed = make_int2(0, 0);
    if (lane < m) ed = ep[base + lane];
    int k = 0;
    for (; k + 3 < m; k += 4) {
      int   sa = __shfl(ed.x, k, 64);
      float wa = __int_as_float(__shfl(ed.y, k, 64));
      int   sb = __shfl(ed.x, k + 1, 64);
      float wb = __int_as_float(__shfl(ed.y, k + 1, 64));
      int   sc = __shfl(ed.x, k + 2, 64);
      float wc = __int_as_float(__shfl(ed.y, k + 2, 64));
      int   sd = __shfl(ed.x, k + 3, 64);
      float wd = __int_as_float(__shfl(ed.y, k + 3, 64));
      if (CH == 128) {
        float2 va = ((const float2*)(xw + (size_t)sa * 128))[lane];
        float2 vb = ((const float2*)(xw + (size_t)sb * 128))[lane];
        float2 vc = ((const float2*)(xw + (size_t)sc * 128))[lane];
        float2 vd = ((const float2*)(xw + (size_t)sd * 128))[lane];
        a0.x = fmaf(wa, va.x, a0.x); a0.y = fmaf(wa, va.y, a0.y);
        a1.x = fmaf(wb, vb.x, a1.x); a1.y = fmaf(wb, vb.y, a1.y);
        a2.x = fmaf(wc, vc.x, a2.x); a2.y = fmaf(wc, vc.y, a2.y);
        a3.x = fmaf(wd, vd.x, a3.x); a3.y = fmaf(wd, vd.y, a3.y);
      } else {
        b0 = fmaf(wa, xw[(size_t)sa * 64 + lane], b0);
        b1 = fmaf(wb, xw[(size_t)sb * 64 + lane], b1);
        b2 = fmaf(wc, xw[(size_t)sc * 64 + lane], b2);
        b3 = fmaf(wd, xw[(size_t)sd * 64 + lane], b3);
      }
    }
    for (; k < m; ++k) {
      int   sa = __shfl(ed.x, k, 64);
      float wa = __int_as_float(__shfl(ed.y, k, 64));
      if (CH == 128) {
        float2 va = ((const float2*)(xw + (size_t)sa * 128))[lane];
        a0.x = fmaf(wa, va.x, a0.x); a0.y = fmaf(wa, va.y, a0.y);
      } else {
        b0 = fmaf(wa, xw[(size_t)sa * 64 + lane], b0);
      }
    }
  }
  float di = deg_inv[node];
  if (CH == 128) {
    float2 sv = ((const float2*)(xw + (size_t)node * 128))[lane];
    float2 bv = ((const float2*)bias)[lane];
    float ox = ((a0.x + a1.x) + (a2.x + a3.x)) + sv.x * di + bv.x;
    float oy = ((a0.y + a1.y) + (a2.y + a3.y)) + sv.y * di + bv.y;
    if (RELU) { ox = fmaxf(ox, 0.f); oy = fmaxf(oy, 0.f); }
    ((float2*)(out + (size_t)node * 128))[lane] = make_float2(ox, oy);
  } else {
    float o = ((b0 + b1) + (b2 + b3)) + xw[(size_t)node * 64 + lane] * di + bias[lane];
    if (RELU) o = fmaxf(o, 0.f);
    out[(size_t)node * 64 + lane] = o;
  }
}

// One wave per label edge: dot(z[src], z[dst]) over 64 channels (round-4).
__global__ __launch_bounds__(256)
void decode_kernel(const float* __restrict__ z, const int* __restrict__ eli,
                   float* __restrict__ out, int nl) {
  int wave = (blockIdx.x * 256 + threadIdx.x) >> 6;
  int lane = threadIdx.x & 63;
  if (wave >= nl) return;
  int src = eli[wave];
  int dst = eli[nl + wave];
  float p = z[(size_t)src * 64 + lane] * z[(size_t)dst * 64 + lane];
#pragma unroll
  for (int m = 32; m >= 1; m >>= 1) p += __shfl_xor(p, m, 64);
  if (lane == 0) out[wave] = p;
}

extern "C" void kernel_launch(void* const* d_in, const int* in_sizes, int n_in,
                              void* d_out, int out_size, void* d_ws, size_t ws_size,
                              hipStream_t stream) {
  const float* x  = (const float*)d_in[0];
  const float* W1 = (const float*)d_in[1];
  const float* b1 = (const float*)d_in[2];
  const float* W2 = (const float*)d_in[3];
  const float* b2 = (const float*)d_in[4];
  const int* eidx = (const int*)d_in[5];
  const int* eli  = (const int*)d_in[6];
  const int N  = in_sizes[0] / 128;
  const int E  = in_sizes[5] / 2;
  const int NL = in_sizes[6] / 2;
  float* out = (float*)d_out;

  char* ws = (char*)d_ws;
  size_t off = 0;
  auto alloc = [&](size_t bytes) -> char* {
    char* p = ws + off;
    off = (off + bytes + 255) & ~(size_t)255;
    return p;
  };
  const int NB = (N + 255) / 256;
  float* dis   = (float*)alloc((size_t)N * 4);
  float* dinv  = (float*)alloc((size_t)N * 4);
  int*   cnt   = (int*)  alloc((size_t)N * 4);
  int*   rowp  = (int*)  alloc((size_t)(N + 1) * 4);
  int*   part  = (int*)  alloc((size_t)NB * 4);
  int2*  ep    = (int2*) alloc((size_t)E * 8);
  float* bufA  = (float*)alloc((size_t)N * 128 * 4);
  float* bufB  = (float*)alloc((size_t)N * 128 * 4);
  (void)ws_size; (void)n_in; (void)out_size;

  const int* row = eidx;      // edge_index[0]
  const int* col = eidx + E;  // edge_index[1]

  hipMemsetAsync(cnt, 0, (size_t)N * 4, stream);
  count_kernel<<<(E + 255) / 256, 256, 0, stream>>>(col, cnt, E);
  partial_deg_kernel<<<NB, 256, 0, stream>>>(cnt, part, dis, dinv, N);
  scan_part_kernel<<<1, 256, 0, stream>>>(part, NB);
  scan_final_kernel<<<NB, 256, 0, stream>>>(cnt, part, rowp, cnt, N);
  fill_kernel<<<(E + 255) / 256, 256, 0, stream>>>(row, col, dis, rowp, cnt, ep, E);
  // conv1
  gemm_kernel<128><<<(N + 31) / 32, 256, 0, stream>>>(x, W1, bufA, N);
  agg_kernel<128, true><<<(N + 3) / 4, 256, 0, stream>>>(bufA, rowp, ep, dinv, b1, bufB, N);
  // conv2
  gemm_kernel<64><<<(N + 31) / 32, 256, 0, stream>>>(bufB, W2, bufA, N);
  agg_kernel<64, false><<<(N + 3) / 4, 256, 0, stream>>>(bufA, rowp, ep, dinv, b2, bufB, N);
  // decode
  decode_kernel<<<(NL + 3) / 4, 256, 0, stream>>>(bufB, eli, out, NL);
}

// Round 7
// 301.923 us; speedup vs baseline: 1.8232x; 1.1000x over previous
//
#include <hip/hip_runtime.h>
#include <hip/hip_bf16.h>
#include <hip/hip_fp16.h>

// ---------------------------------------------------------------------------
// GCN link prediction:
//   deg+partials -> scan(2-level) -> CSR fill (packed int2) ->
//   (X@W1) -> agg+bias+relu -> (@W2) -> agg+bias -> decode dot
// Round 7 = round-6 passing code with ONE concept change: intermediate
// feature tables are fp16 (gather traffic halved; all math still fp32).
//   bufA_h: half[N,128] = x@W1          (conv1 agg gather table)
//   bufB_h: half[N,128] = relu(agg1)    (conv2 gemm input)
//   bufC_h: half[N,64]  = bufB@W2       (conv2 agg gather table)
//   z:      float[N,64] = agg2          (decode input, fp32)
// CSR build, agg loop structure (uniform-broadcast 4-way), decode unchanged.
// ---------------------------------------------------------------------------

__global__ __launch_bounds__(256)
void count_kernel(const int* __restrict__ col, int* __restrict__ cnt, int ne) {
  int e = blockIdx.x * 256 + threadIdx.x;
  if (e < ne) atomicAdd(&cnt[col[e]], 1);
}

__global__ __launch_bounds__(256)
void partial_deg_kernel(const int* __restrict__ cnt, int* __restrict__ part,
                        float* __restrict__ dis, float* __restrict__ dinv, int n) {
  int i = blockIdx.x * 256 + threadIdx.x;
  int c = (i < n) ? cnt[i] : 0;
  if (i < n) {
    float d = (float)(c + 1);   // +1 self loop
    dinv[i] = 1.0f / d;
    dis[i]  = rsqrtf(d);
  }
  int lane = threadIdx.x & 63, w = threadIdx.x >> 6;
  int s = c;
#pragma unroll
  for (int m = 32; m >= 1; m >>= 1) s += __shfl_xor(s, m, 64);
  __shared__ int wp[4];
  if (lane == 0) wp[w] = s;
  __syncthreads();
  if (threadIdx.x == 0) part[blockIdx.x] = wp[0] + wp[1] + wp[2] + wp[3];
}

__device__ inline int wave_incl_scan(int v, int lane) {
#pragma unroll
  for (int off = 1; off < 64; off <<= 1) {
    int u = __shfl_up(v, off, 64);
    if (lane >= off) v += u;
  }
  return v;
}

__global__ __launch_bounds__(256)
void scan_part_kernel(int* __restrict__ part, int nb) {
  int t = threadIdx.x;
  int v = (t < nb) ? part[t] : 0;
  int lane = t & 63, w = t >> 6;
  int inc = wave_incl_scan(v, lane);
  __shared__ int wp[4];
  if (lane == 63) wp[w] = inc;
  __syncthreads();
  if (t == 0) { int s = 0; for (int k = 0; k < 4; ++k) { int x = wp[k]; wp[k] = s; s += x; } }
  __syncthreads();
  int excl = wp[w] + inc - v;
  if (t < nb) part[t] = excl;
}

__global__ __launch_bounds__(256)
void scan_final_kernel(const int* __restrict__ cnt, const int* __restrict__ part,
                       int* __restrict__ row_ptr, int* __restrict__ cur, int n) {
  int t = threadIdx.x;
  int i = blockIdx.x * 256 + t;
  int v = (i < n) ? cnt[i] : 0;
  int lane = t & 63, w = t >> 6;
  int inc = wave_incl_scan(v, lane);
  __shared__ int wp[4];
  if (lane == 63) wp[w] = inc;
  __syncthreads();
  if (t == 0) { int s = 0; for (int k = 0; k < 4; ++k) { int x = wp[k]; wp[k] = s; s += x; } }
  __syncthreads();
  int excl = part[blockIdx.x] + wp[w] + inc - v;
  if (i < n) {
    row_ptr[i] = excl;
    cur[i] = 0;
    if (i == n - 1) row_ptr[n] = excl + v;
  }
}

__global__ __launch_bounds__(256)
void fill_kernel(const int* __restrict__ row, const int* __restrict__ col,
                 const float* __restrict__ dis, const int* __restrict__ row_ptr,
                 int* __restrict__ cur, int2* __restrict__ ep, int ne) {
  int e = blockIdx.x * 256 + threadIdx.x;
  if (e >= ne) return;
  int r = row[e], c = col[e];
  int pos = row_ptr[c] + atomicAdd(&cur[c], 1);
  float nrm = dis[r] * dis[c];
  ep[pos] = make_int2(r, __float_as_int(nrm));
}

// Y[N,M] = X[N,128] @ W[128,M]. W staged in K=32 chunks. fp32 math.
// TIn in {float, __half}; TOut in {float, __half}.
template<int M, typename TIn, typename TOut>
__global__ __launch_bounds__(256)
void gemm_kernel(const TIn* __restrict__ X, const float* __restrict__ W,
                 TOut* __restrict__ Y, int N) {
  constexpr int K = 128;
  constexpr int KC = 32;
  constexpr int ROWS = 32;
  constexpr int XLD = K + 4;
  __shared__ float Ws[KC * M];
  __shared__ float Xs[ROWS * XLD];
  const int t = threadIdx.x;
  const int row0 = blockIdx.x * ROWS;
  if constexpr (sizeof(TIn) == 4) {
    for (int i = t; i < ROWS * K / 4; i += 256) {
      int r  = i >> 5;
      int c4 = i & 31;
      int gr = row0 + r;
      float4 v = make_float4(0.f, 0.f, 0.f, 0.f);
      if (gr < N) v = ((const float4*)((const float*)X + (size_t)gr * K))[c4];
      *(float4*)(&Xs[r * XLD + c4 * 4]) = v;
    }
  } else {
    for (int i = t; i < ROWS * K / 2; i += 256) {
      int r  = i >> 6;      // 64 half2 per row
      int c2 = i & 63;
      int gr = row0 + r;
      float2 v = make_float2(0.f, 0.f);
      if (gr < N)
        v = __half22float2(((const __half2*)((const __half*)X + (size_t)gr * K))[c2]);
      Xs[r * XLD + c2 * 2]     = v.x;
      Xs[r * XLD + c2 * 2 + 1] = v.y;
    }
  }
  constexpr int CGS = M / 4;
  constexpr int RPT = ROWS / (256 / CGS);
  const int cg = t % CGS;
  const int rg = t / CGS;
  const int c0 = cg * 4;
  const int r0 = rg * RPT;
  float acc[RPT][4];
#pragma unroll
  for (int i = 0; i < RPT; ++i)
    acc[i][0] = acc[i][1] = acc[i][2] = acc[i][3] = 0.f;

  for (int k0 = 0; k0 < K; k0 += KC) {
    __syncthreads();
    for (int i = t; i < KC * M / 4; i += 256) {
      int kk = i / (M / 4), cc = i % (M / 4);
      ((float4*)&Ws[kk * M])[cc] = ((const float4*)&W[(size_t)(k0 + kk) * M])[cc];
    }
    __syncthreads();
#pragma unroll 4
    for (int k = 0; k < KC; ++k) {
      float4 wv = *(const float4*)(&Ws[k * M + c0]);
#pragma unroll
      for (int i = 0; i < RPT; ++i) {
        float xv = Xs[(r0 + i) * XLD + (k0 + k)];
        acc[i][0] = fmaf(xv, wv.x, acc[i][0]);
        acc[i][1] = fmaf(xv, wv.y, acc[i][1]);
        acc[i][2] = fmaf(xv, wv.z, acc[i][2]);
        acc[i][3] = fmaf(xv, wv.w, acc[i][3]);
      }
    }
  }
#pragma unroll
  for (int i = 0; i < RPT; ++i) {
    int gr = row0 + r0 + i;
    if (gr < N) {
      if constexpr (sizeof(TOut) == 4) {
        *(float4*)((float*)Y + (size_t)gr * M + c0) =
            make_float4(acc[i][0], acc[i][1], acc[i][2], acc[i][3]);
      } else {
        __half2* yp = (__half2*)((__half*)Y + (size_t)gr * M + c0);
        yp[0] = __float22half2_rn(make_float2(acc[i][0], acc[i][1]));
        yp[1] = __float22half2_rn(make_float2(acc[i][2], acc[i][3]));
      }
    }
  }
}

// CH=128 aggregation, fp16 table in/out. One wave/node; lanes cover channels
// (half2 at [lane] = ch 2*lane, 2*lane+1). Uniform-broadcast 4-way unroll.
template<bool RELU>
__global__ __launch_bounds__(256)
void agg128h_kernel(const __half* __restrict__ xw, const int* __restrict__ row_ptr,
                    const int2* __restrict__ ep, const float* __restrict__ deg_inv,
                    const float* __restrict__ bias, __half* __restrict__ out, int n) {
  int wave = (blockIdx.x * 256 + threadIdx.x) >> 6;
  int lane = threadIdx.x & 63;
  if (wave >= n) return;
  const int node = wave;
  const int s0 = row_ptr[node], s1 = row_ptr[node + 1];
  float2 a0 = make_float2(0.f, 0.f), a1 = make_float2(0.f, 0.f);
  float2 a2 = make_float2(0.f, 0.f), a3 = make_float2(0.f, 0.f);
  for (int base = s0; base < s1; base += 64) {
    int m = s1 - base; if (m > 64) m = 64;
    int2 ed = make_int2(0, 0);
    if (lane < m) ed = ep[base + lane];
    int k = 0;
    for (; k + 3 < m; k += 4) {
      int   sa = __shfl(ed.x, k, 64);
      float wa = __int_as_float(__shfl(ed.y, k, 64));
      int   sb = __shfl(ed.x, k + 1, 64);
      float wb = __int_as_float(__shfl(ed.y, k + 1, 64));
      int   sc = __shfl(ed.x, k + 2, 64);
      float wc = __int_as_float(__shfl(ed.y, k + 2, 64));
      int   sd = __shfl(ed.x, k + 3, 64);
      float wd = __int_as_float(__shfl(ed.y, k + 3, 64));
      float2 va = __half22float2(((const __half2*)(xw + (size_t)sa * 128))[lane]);
      float2 vb = __half22float2(((const __half2*)(xw + (size_t)sb * 128))[lane]);
      float2 vc = __half22float2(((const __half2*)(xw + (size_t)sc * 128))[lane]);
      float2 vd = __half22float2(((const __half2*)(xw + (size_t)sd * 128))[lane]);
      a0.x = fmaf(wa, va.x, a0.x); a0.y = fmaf(wa, va.y, a0.y);
      a1.x = fmaf(wb, vb.x, a1.x); a1.y = fmaf(wb, vb.y, a1.y);
      a2.x = fmaf(wc, vc.x, a2.x); a2.y = fmaf(wc, vc.y, a2.y);
      a3.x = fmaf(wd, vd.x, a3.x); a3.y = fmaf(wd, vd.y, a3.y);
    }
    for (; k < m; ++k) {
      int   sa = __shfl(ed.x, k, 64);
      float wa = __int_as_float(__shfl(ed.y, k, 64));
      float2 va = __half22float2(((const __half2*)(xw + (size_t)sa * 128))[lane]);
      a0.x = fmaf(wa, va.x, a0.x); a0.y = fmaf(wa, va.y, a0.y);
    }
  }
  float di = deg_inv[node];
  float2 sv = __half22float2(((const __half2*)(xw + (size_t)node * 128))[lane]);
  float2 bv = ((const float2*)bias)[lane];
  float ox = ((a0.x + a1.x) + (a2.x + a3.x)) + sv.x * di + bv.x;
  float oy = ((a0.y + a1.y) + (a2.y + a3.y)) + sv.y * di + bv.y;
  if (RELU) { ox = fmaxf(ox, 0.f); oy = fmaxf(oy, 0.f); }
  ((__half2*)(out + (size_t)node * 128))[lane] = __float22half2_rn(make_float2(ox, oy));
}

// CH=64 aggregation, fp16 table in, fp32 out (decode reads fp32).
template<bool RELU>
__global__ __launch_bounds__(256)
void agg64h_kernel(const __half* __restrict__ xw, const int* __restrict__ row_ptr,
                   const int2* __restrict__ ep, const float* __restrict__ deg_inv,
                   const float* __restrict__ bias, float* __restrict__ out, int n) {
  int wave = (blockIdx.x * 256 + threadIdx.x) >> 6;
  int lane = threadIdx.x & 63;
  if (wave >= n) return;
  const int node = wave;
  const int s0 = row_ptr[node], s1 = row_ptr[node + 1];
  float b0 = 0.f, b1 = 0.f, b2 = 0.f, b3 = 0.f;
  for (int base = s0; base < s1; base += 64) {
    int m = s1 - base; if (m > 64) m = 64;
    int2 ed = make_int2(0, 0);
    if (lane < m) ed = ep[base + lane];
    int k = 0;
    for (; k + 3 < m; k += 4) {
      int   sa = __shfl(ed.x, k, 64);
      float wa = __int_as_float(__shfl(ed.y, k, 64));
      int   sb = __shfl(ed.x, k + 1, 64);
      float wb = __int_as_float(__shfl(ed.y, k + 1, 64));
      int   sc = __shfl(ed.x, k + 2, 64);
      float wc = __int_as_float(__shfl(ed.y, k + 2, 64));
      int   sd = __shfl(ed.x, k + 3, 64);
      float wd = __int_as_float(__shfl(ed.y, k + 3, 64));
      b0 = fmaf(wa, __half2float(xw[(size_t)sa * 64 + lane]), b0);
      b1 = fmaf(wb, __half2float(xw[(size_t)sb * 64 + lane]), b1);
      b2 = fmaf(wc, __half2float(xw[(size_t)sc * 64 + lane]), b2);
      b3 = fmaf(wd, __half2float(xw[(size_t)sd * 64 + lane]), b3);
    }
    for (; k < m; ++k) {
      int   sa = __shfl(ed.x, k, 64);
      float wa = __int_as_float(__shfl(ed.y, k, 64));
      b0 = fmaf(wa, __half2float(xw[(size_t)sa * 64 + lane]), b0);
    }
  }
  float di = deg_inv[node];
  float o = ((b0 + b1) + (b2 + b3)) +
            __half2float(xw[(size_t)node * 64 + lane]) * di + bias[lane];
  if (RELU) o = fmaxf(o, 0.f);
  out[(size_t)node * 64 + lane] = o;
}

// One wave per label edge: dot(z[src], z[dst]) over 64 channels (fp32).
__global__ __launch_bounds__(256)
void decode_kernel(const float* __restrict__ z, const int* __restrict__ eli,
                   float* __restrict__ out, int nl) {
  int wave = (blockIdx.x * 256 + threadIdx.x) >> 6;
  int lane = threadIdx.x & 63;
  if (wave >= nl) return;
  int src = eli[wave];
  int dst = eli[nl + wave];
  float p = z[(size_t)src * 64 + lane] * z[(size_t)dst * 64 + lane];
#pragma unroll
  for (int m = 32; m >= 1; m >>= 1) p += __shfl_xor(p, m, 64);
  if (lane == 0) out[wave] = p;
}

extern "C" void kernel_launch(void* const* d_in, const int* in_sizes, int n_in,
                              void* d_out, int out_size, void* d_ws, size_t ws_size,
                              hipStream_t stream) {
  const float* x  = (const float*)d_in[0];
  const float* W1 = (const float*)d_in[1];
  const float* b1 = (const float*)d_in[2];
  const float* W2 = (const float*)d_in[3];
  const float* b2 = (const float*)d_in[4];
  const int* eidx = (const int*)d_in[5];
  const int* eli  = (const int*)d_in[6];
  const int N  = in_sizes[0] / 128;
  const int E  = in_sizes[5] / 2;
  const int NL = in_sizes[6] / 2;
  float* out = (float*)d_out;

  char* ws = (char*)d_ws;
  size_t off = 0;
  auto alloc = [&](size_t bytes) -> char* {
    char* p = ws + off;
    off = (off + bytes + 255) & ~(size_t)255;
    return p;
  };
  const int NB = (N + 255) / 256;
  float*  dis   = (float*) alloc((size_t)N * 4);
  float*  dinv  = (float*) alloc((size_t)N * 4);
  int*    cnt   = (int*)   alloc((size_t)N * 4);
  int*    rowp  = (int*)   alloc((size_t)(N + 1) * 4);
  int*    part  = (int*)   alloc((size_t)NB * 4);
  int2*   ep    = (int2*)  alloc((size_t)E * 8);
  __half* bufA  = (__half*)alloc((size_t)N * 128 * 2);
  __half* bufB  = (__half*)alloc((size_t)N * 128 * 2);
  __half* bufC  = (__half*)alloc((size_t)N * 64 * 2);
  float*  z     = (float*) alloc((size_t)N * 64 * 4);
  (void)ws_size; (void)n_in; (void)out_size;

  const int* row = eidx;      // edge_index[0]
  const int* col = eidx + E;  // edge_index[1]

  hipMemsetAsync(cnt, 0, (size_t)N * 4, stream);
  count_kernel<<<(E + 255) / 256, 256, 0, stream>>>(col, cnt, E);
  partial_deg_kernel<<<NB, 256, 0, stream>>>(cnt, part, dis, dinv, N);
  scan_part_kernel<<<1, 256, 0, stream>>>(part, NB);
  scan_final_kernel<<<NB, 256, 0, stream>>>(cnt, part, rowp, cnt, N);
  fill_kernel<<<(E + 255) / 256, 256, 0, stream>>>(row, col, dis, rowp, cnt, ep, E);
  // conv1: bufA = half(x@W1); bufB = half(relu(agg(bufA)+dinv*bufA+b1))
  gemm_kernel<128, float, __half><<<(N + 31) / 32, 256, 0, stream>>>(x, W1, bufA, N);
  agg128h_kernel<true><<<(N + 3) / 4, 256, 0, stream>>>(bufA, rowp, ep, dinv, b1, bufB, N);
  // conv2: bufC = half(bufB@W2); z = agg(bufC)+dinv*bufC+b2 (fp32)
  gemm_kernel<64, __half, __half><<<(N + 31) / 32, 256, 0, stream>>>(bufB, W2, bufC, N);
  agg64h_kernel<false><<<(N + 3) / 4, 256, 0, stream>>>(bufC, rowp, ep, dinv, b2, z, N);
  // decode
  decode_kernel<<<(NL + 3) / 4, 256, 0, stream>>>(z, eli, out, NL);
}

// Round 8
// 277.879 us; speedup vs baseline: 1.9810x; 1.0865x over previous
//
#include <hip/hip_runtime.h>
#include <hip/hip_bf16.h>
#include <hip/hip_fp16.h>

// ---------------------------------------------------------------------------
// GCN link prediction (all math fp32, fp16 gather tables):
//   count(+rank) -> deg/partials -> scan(2-level) -> CSR fill (no atomic) ->
//   (X@W1)->h16 -> agg128 relu ->h16 -> (@W2)->h16 -> agg64 -> z16 -> decode
// Round 8 = round-7 passing code + (A) z table fp16, (B) edge rank captured
// in count_kernel so fill_kernel needs no atomic.
// ---------------------------------------------------------------------------

__global__ __launch_bounds__(256)
void count_kernel(const int* __restrict__ col, int* __restrict__ cnt,
                  int* __restrict__ eoff, int ne) {
  int e = blockIdx.x * 256 + threadIdx.x;
  if (e < ne) eoff[e] = atomicAdd(&cnt[col[e]], 1);
}

__global__ __launch_bounds__(256)
void partial_deg_kernel(const int* __restrict__ cnt, int* __restrict__ part,
                        float* __restrict__ dis, float* __restrict__ dinv, int n) {
  int i = blockIdx.x * 256 + threadIdx.x;
  int c = (i < n) ? cnt[i] : 0;
  if (i < n) {
    float d = (float)(c + 1);   // +1 self loop
    dinv[i] = 1.0f / d;
    dis[i]  = rsqrtf(d);
  }
  int lane = threadIdx.x & 63, w = threadIdx.x >> 6;
  int s = c;
#pragma unroll
  for (int m = 32; m >= 1; m >>= 1) s += __shfl_xor(s, m, 64);
  __shared__ int wp[4];
  if (lane == 0) wp[w] = s;
  __syncthreads();
  if (threadIdx.x == 0) part[blockIdx.x] = wp[0] + wp[1] + wp[2] + wp[3];
}

__device__ inline int wave_incl_scan(int v, int lane) {
#pragma unroll
  for (int off = 1; off < 64; off <<= 1) {
    int u = __shfl_up(v, off, 64);
    if (lane >= off) v += u;
  }
  return v;
}

__global__ __launch_bounds__(256)
void scan_part_kernel(int* __restrict__ part, int nb) {
  int t = threadIdx.x;
  int v = (t < nb) ? part[t] : 0;
  int lane = t & 63, w = t >> 6;
  int inc = wave_incl_scan(v, lane);
  __shared__ int wp[4];
  if (lane == 63) wp[w] = inc;
  __syncthreads();
  if (t == 0) { int s = 0; for (int k = 0; k < 4; ++k) { int x = wp[k]; wp[k] = s; s += x; } }
  __syncthreads();
  int excl = wp[w] + inc - v;
  if (t < nb) part[t] = excl;
}

__global__ __launch_bounds__(256)
void scan_final_kernel(const int* __restrict__ cnt, const int* __restrict__ part,
                       int* __restrict__ row_ptr, int n) {
  int t = threadIdx.x;
  int i = blockIdx.x * 256 + t;
  int v = (i < n) ? cnt[i] : 0;
  int lane = t & 63, w = t >> 6;
  int inc = wave_incl_scan(v, lane);
  __shared__ int wp[4];
  if (lane == 63) wp[w] = inc;
  __syncthreads();
  if (t == 0) { int s = 0; for (int k = 0; k < 4; ++k) { int x = wp[k]; wp[k] = s; s += x; } }
  __syncthreads();
  int excl = part[blockIdx.x] + wp[w] + inc - v;
  if (i < n) {
    row_ptr[i] = excl;
    if (i == n - 1) row_ptr[n] = excl + v;
  }
}

// No atomic: slot = row_ptr[c] + rank captured during count.
__global__ __launch_bounds__(256)
void fill_kernel(const int* __restrict__ row, const int* __restrict__ col,
                 const int* __restrict__ eoff, const float* __restrict__ dis,
                 const int* __restrict__ row_ptr, int2* __restrict__ ep, int ne) {
  int e = blockIdx.x * 256 + threadIdx.x;
  if (e >= ne) return;
  int r = row[e], c = col[e];
  int pos = row_ptr[c] + eoff[e];
  float nrm = dis[r] * dis[c];
  ep[pos] = make_int2(r, __float_as_int(nrm));
}

// Y[N,M] = X[N,128] @ W[128,M]. W staged in K=32 chunks. fp32 math.
template<int M, typename TIn, typename TOut>
__global__ __launch_bounds__(256)
void gemm_kernel(const TIn* __restrict__ X, const float* __restrict__ W,
                 TOut* __restrict__ Y, int N) {
  constexpr int K = 128;
  constexpr int KC = 32;
  constexpr int ROWS = 32;
  constexpr int XLD = K + 4;
  __shared__ float Ws[KC * M];
  __shared__ float Xs[ROWS * XLD];
  const int t = threadIdx.x;
  const int row0 = blockIdx.x * ROWS;
  if constexpr (sizeof(TIn) == 4) {
    for (int i = t; i < ROWS * K / 4; i += 256) {
      int r  = i >> 5;
      int c4 = i & 31;
      int gr = row0 + r;
      float4 v = make_float4(0.f, 0.f, 0.f, 0.f);
      if (gr < N) v = ((const float4*)((const float*)X + (size_t)gr * K))[c4];
      *(float4*)(&Xs[r * XLD + c4 * 4]) = v;
    }
  } else {
    for (int i = t; i < ROWS * K / 2; i += 256) {
      int r  = i >> 6;      // 64 half2 per row
      int c2 = i & 63;
      int gr = row0 + r;
      float2 v = make_float2(0.f, 0.f);
      if (gr < N)
        v = __half22float2(((const __half2*)((const __half*)X + (size_t)gr * K))[c2]);
      Xs[r * XLD + c2 * 2]     = v.x;
      Xs[r * XLD + c2 * 2 + 1] = v.y;
    }
  }
  constexpr int CGS = M / 4;
  constexpr int RPT = ROWS / (256 / CGS);
  const int cg = t % CGS;
  const int rg = t / CGS;
  const int c0 = cg * 4;
  const int r0 = rg * RPT;
  float acc[RPT][4];
#pragma unroll
  for (int i = 0; i < RPT; ++i)
    acc[i][0] = acc[i][1] = acc[i][2] = acc[i][3] = 0.f;

  for (int k0 = 0; k0 < K; k0 += KC) {
    __syncthreads();
    for (int i = t; i < KC * M / 4; i += 256) {
      int kk = i / (M / 4), cc = i % (M / 4);
      ((float4*)&Ws[kk * M])[cc] = ((const float4*)&W[(size_t)(k0 + kk) * M])[cc];
    }
    __syncthreads();
#pragma unroll 4
    for (int k = 0; k < KC; ++k) {
      float4 wv = *(const float4*)(&Ws[k * M + c0]);
#pragma unroll
      for (int i = 0; i < RPT; ++i) {
        float xv = Xs[(r0 + i) * XLD + (k0 + k)];
        acc[i][0] = fmaf(xv, wv.x, acc[i][0]);
        acc[i][1] = fmaf(xv, wv.y, acc[i][1]);
        acc[i][2] = fmaf(xv, wv.z, acc[i][2]);
        acc[i][3] = fmaf(xv, wv.w, acc[i][3]);
      }
    }
  }
#pragma unroll
  for (int i = 0; i < RPT; ++i) {
    int gr = row0 + r0 + i;
    if (gr < N) {
      if constexpr (sizeof(TOut) == 4) {
        *(float4*)((float*)Y + (size_t)gr * M + c0) =
            make_float4(acc[i][0], acc[i][1], acc[i][2], acc[i][3]);
      } else {
        __half2* yp = (__half2*)((__half*)Y + (size_t)gr * M + c0);
        yp[0] = __float22half2_rn(make_float2(acc[i][0], acc[i][1]));
        yp[1] = __float22half2_rn(make_float2(acc[i][2], acc[i][3]));
      }
    }
  }
}

// CH=128 aggregation, fp16 table in/out. Uniform-broadcast 4-way unroll.
template<bool RELU>
__global__ __launch_bounds__(256)
void agg128h_kernel(const __half* __restrict__ xw, const int* __restrict__ row_ptr,
                    const int2* __restrict__ ep, const float* __restrict__ deg_inv,
                    const float* __restrict__ bias, __half* __restrict__ out, int n) {
  int wave = (blockIdx.x * 256 + threadIdx.x) >> 6;
  int lane = threadIdx.x & 63;
  if (wave >= n) return;
  const int node = wave;
  const int s0 = row_ptr[node], s1 = row_ptr[node + 1];
  float2 a0 = make_float2(0.f, 0.f), a1 = make_float2(0.f, 0.f);
  float2 a2 = make_float2(0.f, 0.f), a3 = make_float2(0.f, 0.f);
  for (int base = s0; base < s1; base += 64) {
    int m = s1 - base; if (m > 64) m = 64;
    int2 ed = make_int2(0, 0);
    if (lane < m) ed = ep[base + lane];
    int k = 0;
    for (; k + 3 < m; k += 4) {
      int   sa = __shfl(ed.x, k, 64);
      float wa = __int_as_float(__shfl(ed.y, k, 64));
      int   sb = __shfl(ed.x, k + 1, 64);
      float wb = __int_as_float(__shfl(ed.y, k + 1, 64));
      int   sc = __shfl(ed.x, k + 2, 64);
      float wc = __int_as_float(__shfl(ed.y, k + 2, 64));
      int   sd = __shfl(ed.x, k + 3, 64);
      float wd = __int_as_float(__shfl(ed.y, k + 3, 64));
      float2 va = __half22float2(((const __half2*)(xw + (size_t)sa * 128))[lane]);
      float2 vb = __half22float2(((const __half2*)(xw + (size_t)sb * 128))[lane]);
      float2 vc = __half22float2(((const __half2*)(xw + (size_t)sc * 128))[lane]);
      float2 vd = __half22float2(((const __half2*)(xw + (size_t)sd * 128))[lane]);
      a0.x = fmaf(wa, va.x, a0.x); a0.y = fmaf(wa, va.y, a0.y);
      a1.x = fmaf(wb, vb.x, a1.x); a1.y = fmaf(wb, vb.y, a1.y);
      a2.x = fmaf(wc, vc.x, a2.x); a2.y = fmaf(wc, vc.y, a2.y);
      a3.x = fmaf(wd, vd.x, a3.x); a3.y = fmaf(wd, vd.y, a3.y);
    }
    for (; k < m; ++k) {
      int   sa = __shfl(ed.x, k, 64);
      float wa = __int_as_float(__shfl(ed.y, k, 64));
      float2 va = __half22float2(((const __half2*)(xw + (size_t)sa * 128))[lane]);
      a0.x = fmaf(wa, va.x, a0.x); a0.y = fmaf(wa, va.y, a0.y);
    }
  }
  float di = deg_inv[node];
  float2 sv = __half22float2(((const __half2*)(xw + (size_t)node * 128))[lane]);
  float2 bv = ((const float2*)bias)[lane];
  float ox = ((a0.x + a1.x) + (a2.x + a3.x)) + sv.x * di + bv.x;
  float oy = ((a0.y + a1.y) + (a2.y + a3.y)) + sv.y * di + bv.y;
  if (RELU) { ox = fmaxf(ox, 0.f); oy = fmaxf(oy, 0.f); }
  ((__half2*)(out + (size_t)node * 128))[lane] = __float22half2_rn(make_float2(ox, oy));
}

// CH=64 aggregation, fp16 table in, fp16 out (decode reads fp16 z).
template<bool RELU>
__global__ __launch_bounds__(256)
void agg64h_kernel(const __half* __restrict__ xw, const int* __restrict__ row_ptr,
                   const int2* __restrict__ ep, const float* __restrict__ deg_inv,
                   const float* __restrict__ bias, __half* __restrict__ out, int n) {
  int wave = (blockIdx.x * 256 + threadIdx.x) >> 6;
  int lane = threadIdx.x & 63;
  if (wave >= n) return;
  const int node = wave;
  const int s0 = row_ptr[node], s1 = row_ptr[node + 1];
  float b0 = 0.f, b1 = 0.f, b2 = 0.f, b3 = 0.f;
  for (int base = s0; base < s1; base += 64) {
    int m = s1 - base; if (m > 64) m = 64;
    int2 ed = make_int2(0, 0);
    if (lane < m) ed = ep[base + lane];
    int k = 0;
    for (; k + 3 < m; k += 4) {
      int   sa = __shfl(ed.x, k, 64);
      float wa = __int_as_float(__shfl(ed.y, k, 64));
      int   sb = __shfl(ed.x, k + 1, 64);
      float wb = __int_as_float(__shfl(ed.y, k + 1, 64));
      int   sc = __shfl(ed.x, k + 2, 64);
      float wc = __int_as_float(__shfl(ed.y, k + 2, 64));
      int   sd = __shfl(ed.x, k + 3, 64);
      float wd = __int_as_float(__shfl(ed.y, k + 3, 64));
      b0 = fmaf(wa, __half2float(xw[(size_t)sa * 64 + lane]), b0);
      b1 = fmaf(wb, __half2float(xw[(size_t)sb * 64 + lane]), b1);
      b2 = fmaf(wc, __half2float(xw[(size_t)sc * 64 + lane]), b2);
      b3 = fmaf(wd, __half2float(xw[(size_t)sd * 64 + lane]), b3);
    }
    for (; k < m; ++k) {
      int   sa = __shfl(ed.x, k, 64);
      float wa = __int_as_float(__shfl(ed.y, k, 64));
      b0 = fmaf(wa, __half2float(xw[(size_t)sa * 64 + lane]), b0);
    }
  }
  float di = deg_inv[node];
  float o = ((b0 + b1) + (b2 + b3)) +
            __half2float(xw[(size_t)node * 64 + lane]) * di + bias[lane];
  if (RELU) o = fmaxf(o, 0.f);
  out[(size_t)node * 64 + lane] = __float2half_rn(o);
}

// One wave per label edge: dot(z[src], z[dst]) over 64 fp16 channels.
__global__ __launch_bounds__(256)
void decode_kernel(const __half* __restrict__ z, const int* __restrict__ eli,
                   float* __restrict__ out, int nl) {
  int wave = (blockIdx.x * 256 + threadIdx.x) >> 6;
  int lane = threadIdx.x & 63;
  if (wave >= nl) return;
  int src = eli[wave];
  int dst = eli[nl + wave];
  float a = __half2float(z[(size_t)src * 64 + lane]);
  float b = __half2float(z[(size_t)dst * 64 + lane]);
  float p = a * b;
#pragma unroll
  for (int m = 32; m >= 1; m >>= 1) p += __shfl_xor(p, m, 64);
  if (lane == 0) out[wave] = p;
}

extern "C" void kernel_launch(void* const* d_in, const int* in_sizes, int n_in,
                              void* d_out, int out_size, void* d_ws, size_t ws_size,
                              hipStream_t stream) {
  const float* x  = (const float*)d_in[0];
  const float* W1 = (const float*)d_in[1];
  const float* b1 = (const float*)d_in[2];
  const float* W2 = (const float*)d_in[3];
  const float* b2 = (const float*)d_in[4];
  const int* eidx = (const int*)d_in[5];
  const int* eli  = (const int*)d_in[6];
  const int N  = in_sizes[0] / 128;
  const int E  = in_sizes[5] / 2;
  const int NL = in_sizes[6] / 2;
  float* out = (float*)d_out;

  char* ws = (char*)d_ws;
  size_t off = 0;
  auto alloc = [&](size_t bytes) -> char* {
    char* p = ws + off;
    off = (off + bytes + 255) & ~(size_t)255;
    return p;
  };
  const int NB = (N + 255) / 256;
  float*  dis   = (float*) alloc((size_t)N * 4);
  float*  dinv  = (float*) alloc((size_t)N * 4);
  int*    cnt   = (int*)   alloc((size_t)N * 4);
  int*    rowp  = (int*)   alloc((size_t)(N + 1) * 4);
  int*    part  = (int*)   alloc((size_t)NB * 4);
  int*    eoff  = (int*)   alloc((size_t)E * 4);
  int2*   ep    = (int2*)  alloc((size_t)E * 8);
  __half* bufA  = (__half*)alloc((size_t)N * 128 * 2);
  __half* bufB  = (__half*)alloc((size_t)N * 128 * 2);
  __half* bufC  = (__half*)alloc((size_t)N * 64 * 2);
  __half* z     = (__half*)alloc((size_t)N * 64 * 2);
  (void)ws_size; (void)n_in; (void)out_size;

  const int* row = eidx;      // edge_index[0]
  const int* col = eidx + E;  // edge_index[1]

  hipMemsetAsync(cnt, 0, (size_t)N * 4, stream);
  count_kernel<<<(E + 255) / 256, 256, 0, stream>>>(col, cnt, eoff, E);
  partial_deg_kernel<<<NB, 256, 0, stream>>>(cnt, part, dis, dinv, N);
  scan_part_kernel<<<1, 256, 0, stream>>>(part, NB);
  scan_final_kernel<<<NB, 256, 0, stream>>>(cnt, part, rowp, N);
  fill_kernel<<<(E + 255) / 256, 256, 0, stream>>>(row, col, eoff, dis, rowp, ep, E);
  // conv1: bufA = half(x@W1); bufB = half(relu(agg(bufA)+dinv*bufA+b1))
  gemm_kernel<128, float, __half><<<(N + 31) / 32, 256, 0, stream>>>(x, W1, bufA, N);
  agg128h_kernel<true><<<(N + 3) / 4, 256, 0, stream>>>(bufA, rowp, ep, dinv, b1, bufB, N);
  // conv2: bufC = half(bufB@W2); z = half(agg(bufC)+dinv*bufC+b2)
  gemm_kernel<64, __half, __half><<<(N + 31) / 32, 256, 0, stream>>>(bufB, W2, bufC, N);
  agg64h_kernel<false><<<(N + 3) / 4, 256, 0, stream>>>(bufC, rowp, ep, dinv, b2, z, N);
  // decode
  decode_kernel<<<(NL + 3) / 4, 256, 0, stream>>>(z, eli, out, NL);
}

// Round 9
// 269.847 us; speedup vs baseline: 2.0399x; 1.0298x over previous
//
#include <hip/hip_runtime.h>
#include <hip/hip_bf16.h>
#include <hip/hip_fp16.h>

// ---------------------------------------------------------------------------
// GCN link prediction (math fp32, fp16 tables, MFMA GEMMs):
//   prep(x->fp16, W->fp16 transposed) -> count(+rank) -> deg/partials ->
//   scan(2-level) -> CSR fill(no atomic) -> mfma gemm1 -> agg128 relu ->
//   mfma gemm2 -> agg64 -> decode
// Round 9 = round-8 passing code with ONE concept change: the two GEMMs use
// v_mfma_f32_16x16x32_f16 reading fp16 operands directly from global (Wt is
// 32KB, L1-resident); prep kernel makes Xh/W1t/W2t. Everything else identical.
// ---------------------------------------------------------------------------

typedef _Float16 half8 __attribute__((ext_vector_type(8)));
typedef _Float16 half4v __attribute__((ext_vector_type(4)));
typedef float   floatx4 __attribute__((ext_vector_type(4)));

__global__ __launch_bounds__(256)
void count_kernel(const int* __restrict__ col, int* __restrict__ cnt,
                  int* __restrict__ eoff, int ne) {
  int e = blockIdx.x * 256 + threadIdx.x;
  if (e < ne) eoff[e] = atomicAdd(&cnt[col[e]], 1);
}

// Convert x -> fp16 Xh[N][128]; W1[128][128] -> W1t[n][k]; W2[128][64] -> W2t[n][k].
__global__ __launch_bounds__(256)
void prep_kernel(const float* __restrict__ x, const float* __restrict__ W1,
                 const float* __restrict__ W2, _Float16* __restrict__ Xh,
                 _Float16* __restrict__ W1t, _Float16* __restrict__ W2t, int n4) {
  int i = blockIdx.x * 256 + threadIdx.x;
  if (i < n4) {
    float4 v = ((const float4*)x)[i];
    half4v h; h[0] = (_Float16)v.x; h[1] = (_Float16)v.y;
    h[2] = (_Float16)v.z; h[3] = (_Float16)v.w;
    ((half4v*)Xh)[i] = h;
  }
  if (i < 128 * 128) {  // W1t[n*128+k] = W1[k*128+n]
    int k = i >> 7, n = i & 127;
    W1t[(size_t)n * 128 + k] = (_Float16)W1[i];
  }
  if (i < 128 * 64) {   // W2t[n*128+k] = W2[k*64+n]
    int k = i >> 6, n = i & 63;
    W2t[(size_t)n * 128 + k] = (_Float16)W2[i];
  }
}

__global__ __launch_bounds__(256)
void partial_deg_kernel(const int* __restrict__ cnt, int* __restrict__ part,
                        float* __restrict__ dis, float* __restrict__ dinv, int n) {
  int i = blockIdx.x * 256 + threadIdx.x;
  int c = (i < n) ? cnt[i] : 0;
  if (i < n) {
    float d = (float)(c + 1);   // +1 self loop
    dinv[i] = 1.0f / d;
    dis[i]  = rsqrtf(d);
  }
  int lane = threadIdx.x & 63, w = threadIdx.x >> 6;
  int s = c;
#pragma unroll
  for (int m = 32; m >= 1; m >>= 1) s += __shfl_xor(s, m, 64);
  __shared__ int wp[4];
  if (lane == 0) wp[w] = s;
  __syncthreads();
  if (threadIdx.x == 0) part[blockIdx.x] = wp[0] + wp[1] + wp[2] + wp[3];
}

__device__ inline int wave_incl_scan(int v, int lane) {
#pragma unroll
  for (int off = 1; off < 64; off <<= 1) {
    int u = __shfl_up(v, off, 64);
    if (lane >= off) v += u;
  }
  return v;
}

__global__ __launch_bounds__(256)
void scan_part_kernel(int* __restrict__ part, int nb) {
  int t = threadIdx.x;
  int v = (t < nb) ? part[t] : 0;
  int lane = t & 63, w = t >> 6;
  int inc = wave_incl_scan(v, lane);
  __shared__ int wp[4];
  if (lane == 63) wp[w] = inc;
  __syncthreads();
  if (t == 0) { int s = 0; for (int k = 0; k < 4; ++k) { int x = wp[k]; wp[k] = s; s += x; } }
  __syncthreads();
  int excl = wp[w] + inc - v;
  if (t < nb) part[t] = excl;
}

__global__ __launch_bounds__(256)
void scan_final_kernel(const int* __restrict__ cnt, const int* __restrict__ part,
                       int* __restrict__ row_ptr, int n) {
  int t = threadIdx.x;
  int i = blockIdx.x * 256 + t;
  int v = (i < n) ? cnt[i] : 0;
  int lane = t & 63, w = t >> 6;
  int inc = wave_incl_scan(v, lane);
  __shared__ int wp[4];
  if (lane == 63) wp[w] = inc;
  __syncthreads();
  if (t == 0) { int s = 0; for (int k = 0; k < 4; ++k) { int x = wp[k]; wp[k] = s; s += x; } }
  __syncthreads();
  int excl = part[blockIdx.x] + wp[w] + inc - v;
  if (i < n) {
    row_ptr[i] = excl;
    if (i == n - 1) row_ptr[n] = excl + v;
  }
}

__global__ __launch_bounds__(256)
void fill_kernel(const int* __restrict__ row, const int* __restrict__ col,
                 const int* __restrict__ eoff, const float* __restrict__ dis,
                 const int* __restrict__ row_ptr, int2* __restrict__ ep, int ne) {
  int e = blockIdx.x * 256 + threadIdx.x;
  if (e >= ne) return;
  int r = row[e], c = col[e];
  int pos = row_ptr[c] + eoff[e];
  float nrm = dis[r] * dis[c];
  ep[pos] = make_int2(r, __float_as_int(nrm));
}

// Y[N,M] = Xh[N,128] @ Wt^T  (Wt is [M rows n][128 k], fp16).
// Block = 64 rows (4 waves x 16-row bands); wave does all M/16 col-tiles.
// Fragments straight from global: A m=lane&15,k=quad*8+j; B n=lane&15,
// k=quad*8+j; D col=lane&15,row=quad*4+r (HW-verified C/D map).
template<int M>
__global__ __launch_bounds__(256)
void gemm_mfma_kernel(const _Float16* __restrict__ Xh,
                      const _Float16* __restrict__ Wt,
                      _Float16* __restrict__ Y, int N) {
  constexpr int K = 128;
  constexpr int CT = M / 16;
  const int t = threadIdx.x;
  const int lane = t & 63;
  const int i16 = lane & 15;
  const int quad = lane >> 4;
  const int row0 = blockIdx.x * 64 + (t >> 6) * 16;  // wave's 16-row band
  int arow = row0 + i16;
  if (arow >= N) arow = N - 1;   // clamped rows produce D rows we never write
  const _Float16* aptr = Xh + (size_t)arow * K + quad * 8;
  floatx4 acc[CT];
#pragma unroll
  for (int c = 0; c < CT; ++c) acc[c] = (floatx4){0.f, 0.f, 0.f, 0.f};
#pragma unroll
  for (int k0 = 0; k0 < K; k0 += 32) {
    half8 a = *(const half8*)(aptr + k0);
#pragma unroll
    for (int c = 0; c < CT; ++c) {
      half8 b = *(const half8*)(Wt + (size_t)(c * 16 + i16) * K + quad * 8 + k0);
      acc[c] = __builtin_amdgcn_mfma_f32_16x16x32_f16(a, b, acc[c], 0, 0, 0);
    }
  }
#pragma unroll
  for (int c = 0; c < CT; ++c) {
#pragma unroll
    for (int r = 0; r < 4; ++r) {
      int gr = row0 + quad * 4 + r;
      if (gr < N) Y[(size_t)gr * M + c * 16 + i16] = (_Float16)acc[c][r];
    }
  }
}

// CH=128 aggregation, fp16 table in/out. Uniform-broadcast 4-way unroll.
template<bool RELU>
__global__ __launch_bounds__(256)
void agg128h_kernel(const __half* __restrict__ xw, const int* __restrict__ row_ptr,
                    const int2* __restrict__ ep, const float* __restrict__ deg_inv,
                    const float* __restrict__ bias, __half* __restrict__ out, int n) {
  int wave = (blockIdx.x * 256 + threadIdx.x) >> 6;
  int lane = threadIdx.x & 63;
  if (wave >= n) return;
  const int node = wave;
  const int s0 = row_ptr[node], s1 = row_ptr[node + 1];
  float2 a0 = make_float2(0.f, 0.f), a1 = make_float2(0.f, 0.f);
  float2 a2 = make_float2(0.f, 0.f), a3 = make_float2(0.f, 0.f);
  for (int base = s0; base < s1; base += 64) {
    int m = s1 - base; if (m > 64) m = 64;
    int2 ed = make_int2(0, 0);
    if (lane < m) ed = ep[base + lane];
    int k = 0;
    for (; k + 3 < m; k += 4) {
      int   sa = __shfl(ed.x, k, 64);
      float wa = __int_as_float(__shfl(ed.y, k, 64));
      int   sb = __shfl(ed.x, k + 1, 64);
      float wb = __int_as_float(__shfl(ed.y, k + 1, 64));
      int   sc = __shfl(ed.x, k + 2, 64);
      float wc = __int_as_float(__shfl(ed.y, k + 2, 64));
      int   sd = __shfl(ed.x, k + 3, 64);
      float wd = __int_as_float(__shfl(ed.y, k + 3, 64));
      float2 va = __half22float2(((const __half2*)(xw + (size_t)sa * 128))[lane]);
      float2 vb = __half22float2(((const __half2*)(xw + (size_t)sb * 128))[lane]);
      float2 vc = __half22float2(((const __half2*)(xw + (size_t)sc * 128))[lane]);
      float2 vd = __half22float2(((const __half2*)(xw + (size_t)sd * 128))[lane]);
      a0.x = fmaf(wa, va.x, a0.x); a0.y = fmaf(wa, va.y, a0.y);
      a1.x = fmaf(wb, vb.x, a1.x); a1.y = fmaf(wb, vb.y, a1.y);
      a2.x = fmaf(wc, vc.x, a2.x); a2.y = fmaf(wc, vc.y, a2.y);
      a3.x = fmaf(wd, vd.x, a3.x); a3.y = fmaf(wd, vd.y, a3.y);
    }
    for (; k < m; ++k) {
      int   sa = __shfl(ed.x, k, 64);
      float wa = __int_as_float(__shfl(ed.y, k, 64));
      float2 va = __half22float2(((const __half2*)(xw + (size_t)sa * 128))[lane]);
      a0.x = fmaf(wa, va.x, a0.x); a0.y = fmaf(wa, va.y, a0.y);
    }
  }
  float di = deg_inv[node];
  float2 sv = __half22float2(((const __half2*)(xw + (size_t)node * 128))[lane]);
  float2 bv = ((const float2*)bias)[lane];
  float ox = ((a0.x + a1.x) + (a2.x + a3.x)) + sv.x * di + bv.x;
  float oy = ((a0.y + a1.y) + (a2.y + a3.y)) + sv.y * di + bv.y;
  if (RELU) { ox = fmaxf(ox, 0.f); oy = fmaxf(oy, 0.f); }
  ((__half2*)(out + (size_t)node * 128))[lane] = __float22half2_rn(make_float2(ox, oy));
}

// CH=64 aggregation, fp16 table in, fp16 out.
template<bool RELU>
__global__ __launch_bounds__(256)
void agg64h_kernel(const __half* __restrict__ xw, const int* __restrict__ row_ptr,
                   const int2* __restrict__ ep, const float* __restrict__ deg_inv,
                   const float* __restrict__ bias, __half* __restrict__ out, int n) {
  int wave = (blockIdx.x * 256 + threadIdx.x) >> 6;
  int lane = threadIdx.x & 63;
  if (wave >= n) return;
  const int node = wave;
  const int s0 = row_ptr[node], s1 = row_ptr[node + 1];
  float b0 = 0.f, b1 = 0.f, b2 = 0.f, b3 = 0.f;
  for (int base = s0; base < s1; base += 64) {
    int m = s1 - base; if (m > 64) m = 64;
    int2 ed = make_int2(0, 0);
    if (lane < m) ed = ep[base + lane];
    int k = 0;
    for (; k + 3 < m; k += 4) {
      int   sa = __shfl(ed.x, k, 64);
      float wa = __int_as_float(__shfl(ed.y, k, 64));
      int   sb = __shfl(ed.x, k + 1, 64);
      float wb = __int_as_float(__shfl(ed.y, k + 1, 64));
      int   sc = __shfl(ed.x, k + 2, 64);
      float wc = __int_as_float(__shfl(ed.y, k + 2, 64));
      int   sd = __shfl(ed.x, k + 3, 64);
      float wd = __int_as_float(__shfl(ed.y, k + 3, 64));
      b0 = fmaf(wa, __half2float(xw[(size_t)sa * 64 + lane]), b0);
      b1 = fmaf(wb, __half2float(xw[(size_t)sb * 64 + lane]), b1);
      b2 = fmaf(wc, __half2float(xw[(size_t)sc * 64 + lane]), b2);
      b3 = fmaf(wd, __half2float(xw[(size_t)sd * 64 + lane]), b3);
    }
    for (; k < m; ++k) {
      int   sa = __shfl(ed.x, k, 64);
      float wa = __int_as_float(__shfl(ed.y, k, 64));
      b0 = fmaf(wa, __half2float(xw[(size_t)sa * 64 + lane]), b0);
    }
  }
  float di = deg_inv[node];
  float o = ((b0 + b1) + (b2 + b3)) +
            __half2float(xw[(size_t)node * 64 + lane]) * di + bias[lane];
  if (RELU) o = fmaxf(o, 0.f);
  out[(size_t)node * 64 + lane] = __float2half_rn(o);
}

// One wave per label edge: dot(z[src], z[dst]) over 64 fp16 channels.
__global__ __launch_bounds__(256)
void decode_kernel(const __half* __restrict__ z, const int* __restrict__ eli,
                   float* __restrict__ out, int nl) {
  int wave = (blockIdx.x * 256 + threadIdx.x) >> 6;
  int lane = threadIdx.x & 63;
  if (wave >= nl) return;
  int src = eli[wave];
  int dst = eli[nl + wave];
  float a = __half2float(z[(size_t)src * 64 + lane]);
  float b = __half2float(z[(size_t)dst * 64 + lane]);
  float p = a * b;
#pragma unroll
  for (int m = 32; m >= 1; m >>= 1) p += __shfl_xor(p, m, 64);
  if (lane == 0) out[wave] = p;
}

extern "C" void kernel_launch(void* const* d_in, const int* in_sizes, int n_in,
                              void* d_out, int out_size, void* d_ws, size_t ws_size,
                              hipStream_t stream) {
  const float* x  = (const float*)d_in[0];
  const float* W1 = (const float*)d_in[1];
  const float* b1 = (const float*)d_in[2];
  const float* W2 = (const float*)d_in[3];
  const float* b2 = (const float*)d_in[4];
  const int* eidx = (const int*)d_in[5];
  const int* eli  = (const int*)d_in[6];
  const int N  = in_sizes[0] / 128;
  const int E  = in_sizes[5] / 2;
  const int NL = in_sizes[6] / 2;
  float* out = (float*)d_out;

  char* ws = (char*)d_ws;
  size_t off = 0;
  auto alloc = [&](size_t bytes) -> char* {
    char* p = ws + off;
    off = (off + bytes + 255) & ~(size_t)255;
    return p;
  };
  const int NB = (N + 255) / 256;
  float*    dis   = (float*)   alloc((size_t)N * 4);
  float*    dinv  = (float*)   alloc((size_t)N * 4);
  int*      cnt   = (int*)     alloc((size_t)N * 4);
  int*      rowp  = (int*)     alloc((size_t)(N + 1) * 4);
  int*      part  = (int*)     alloc((size_t)NB * 4);
  int*      eoff  = (int*)     alloc((size_t)E * 4);
  int2*     ep    = (int2*)    alloc((size_t)E * 8);
  _Float16* Xh    = (_Float16*)alloc((size_t)N * 128 * 2);
  _Float16* W1t   = (_Float16*)alloc((size_t)128 * 128 * 2);
  _Float16* W2t   = (_Float16*)alloc((size_t)64 * 128 * 2);
  __half*   bufA  = (__half*)  alloc((size_t)N * 128 * 2);
  __half*   bufB  = (__half*)  alloc((size_t)N * 128 * 2);
  __half*   bufC  = (__half*)  alloc((size_t)N * 64 * 2);
  __half*   z     = (__half*)  alloc((size_t)N * 64 * 2);
  (void)ws_size; (void)n_in; (void)out_size;

  const int* row = eidx;      // edge_index[0]
  const int* col = eidx + E;  // edge_index[1]

  hipMemsetAsync(cnt, 0, (size_t)N * 4, stream);
  const int n4 = N * 32;  // N*128/4 float4 groups
  prep_kernel<<<(n4 + 255) / 256, 256, 0, stream>>>(x, W1, W2, Xh, W1t, W2t, n4);
  count_kernel<<<(E + 255) / 256, 256, 0, stream>>>(col, cnt, eoff, E);
  partial_deg_kernel<<<NB, 256, 0, stream>>>(cnt, part, dis, dinv, N);
  scan_part_kernel<<<1, 256, 0, stream>>>(part, NB);
  scan_final_kernel<<<NB, 256, 0, stream>>>(cnt, part, rowp, N);
  fill_kernel<<<(E + 255) / 256, 256, 0, stream>>>(row, col, eoff, dis, rowp, ep, E);
  // conv1: bufA = half(Xh@W1); bufB = half(relu(agg(bufA)+dinv*bufA+b1))
  gemm_mfma_kernel<128><<<(N + 63) / 64, 256, 0, stream>>>(Xh, W1t, (_Float16*)bufA, N);
  agg128h_kernel<true><<<(N + 3) / 4, 256, 0, stream>>>(bufA, rowp, ep, dinv, b1, bufB, N);
  // conv2: bufC = half(bufB@W2); z = half(agg(bufC)+dinv*bufC+b2)
  gemm_mfma_kernel<64><<<(N + 63) / 64, 256, 0, stream>>>((const _Float16*)bufB, W2t,
                                                          (_Float16*)bufC, N);
  agg64h_kernel<false><<<(N + 3) / 4, 256, 0, stream>>>(bufC, rowp, ep, dinv, b2, z, N);
  // decode
  decode_kernel<<<(NL + 3) / 4, 256, 0, stream>>>(z, eli, out, NL);
}